// Round 1
// baseline (1008.212 us; speedup 1.0000x reference)
//
#include <hip/hip_runtime.h>
#include <hip/hip_bf16.h>
#include <math.h>

// Problem constants (B, N, D_IN, H, F) = (2, 2048, 512, 8, 64)
#define Bq   2
#define Nq   2048
#define DIN  512
#define Hq   8
#define Fq   64
#define NEG  0.2f

// ---------------------------------------------------------------------------
// Kernel 1: mapped = nodes @ W   (4096 x 512) @ (512 x 512), fp32
// 64x64 block tile, BK=16, 256 threads, 4x4 micro-tile per thread.
// ---------------------------------------------------------------------------
#define BM 64
#define BN 64
#define BK 16

__global__ __launch_bounds__(256) void gemm_kernel(
    const float* __restrict__ A,   // nodes  (4096 x 512)
    const float* __restrict__ Bw,  // W      (512 x 512)
    float* __restrict__ C)         // mapped (4096 x 512)
{
    __shared__ __align__(16) float As[BK][BM + 4];  // As[k][m], stride 68
    __shared__ __align__(16) float Bs[BK][BN + 4];  // Bs[k][n], stride 68

    const int t  = threadIdx.x;
    const int m0 = blockIdx.x * BM;       // 0..4032
    const int n0 = blockIdx.y * BN;       // 0..448
    const int tx = t % 16;                // n-group
    const int ty = t / 16;                // m-group

    // staging indices
    const int lr   = t / 4;               // 0..63 : A row
    const int lc   = (t % 4) * 4;         // 0,4,8,12 : A k-quad
    const int brow = t / 16;              // 0..15 : B k-row
    const int bcol = (t % 16) * 4;        // 0..60 : B n-quad

    float acc[4][4];
#pragma unroll
    for (int i = 0; i < 4; i++)
#pragma unroll
        for (int j = 0; j < 4; j++) acc[i][j] = 0.f;

    for (int k0 = 0; k0 < DIN; k0 += BK) {
        float4 av = *(const float4*)&A[(size_t)(m0 + lr) * DIN + k0 + lc];
        float4 bv = *(const float4*)&Bw[(size_t)(k0 + brow) * (Hq * Fq) + n0 + bcol];
        __syncthreads();   // previous stage's reads complete
        As[lc + 0][lr] = av.x;
        As[lc + 1][lr] = av.y;
        As[lc + 2][lr] = av.z;
        As[lc + 3][lr] = av.w;
        *(float4*)&Bs[brow][bcol] = bv;
        __syncthreads();
#pragma unroll
        for (int k = 0; k < BK; k++) {
            float4 a4 = *(const float4*)&As[k][ty * 4];
            float4 b4 = *(const float4*)&Bs[k][tx * 4];
            acc[0][0] += a4.x * b4.x; acc[0][1] += a4.x * b4.y; acc[0][2] += a4.x * b4.z; acc[0][3] += a4.x * b4.w;
            acc[1][0] += a4.y * b4.x; acc[1][1] += a4.y * b4.y; acc[1][2] += a4.y * b4.z; acc[1][3] += a4.y * b4.w;
            acc[2][0] += a4.z * b4.x; acc[2][1] += a4.z * b4.y; acc[2][2] += a4.z * b4.z; acc[2][3] += a4.z * b4.w;
            acc[3][0] += a4.w * b4.x; acc[3][1] += a4.w * b4.y; acc[3][2] += a4.w * b4.z; acc[3][3] += a4.w * b4.w;
        }
    }
#pragma unroll
    for (int i = 0; i < 4; i++) {
        float4 o = make_float4(acc[i][0], acc[i][1], acc[i][2], acc[i][3]);
        *(float4*)&C[(size_t)(m0 + ty * 4 + i) * (Hq * Fq) + n0 + tx * 4] = o;
    }
}

// ---------------------------------------------------------------------------
// Kernel 2: el[w] = sum_f mapped[w*64+f]*a[f]; er[w] = sum_f mapped[w*64+f]*a[64+f]
// one wave per w in [0, B*N*H)
// ---------------------------------------------------------------------------
__global__ __launch_bounds__(256) void elr_kernel(
    const float* __restrict__ mapped, const float* __restrict__ a,
    float* __restrict__ el, float* __restrict__ er)
{
    const int w    = (blockIdx.x * 256 + threadIdx.x) >> 6;   // 0..32767
    const int lane = threadIdx.x & 63;
    float v  = mapped[(size_t)w * Fq + lane];
    float pl = v * a[lane];
    float pr = v * a[Fq + lane];
#pragma unroll
    for (int off = 32; off > 0; off >>= 1) {
        pl += __shfl_xor(pl, off, 64);
        pr += __shfl_xor(pr, off, 64);
    }
    if (lane == 0) { el[w] = pl; er[w] = pr; }
}

// ---------------------------------------------------------------------------
// Kernel 3: flash-style masked attention, rank-1 scores.
// One wave (64 threads) per (b, h, 16-row i-tile). j-tiles of 64.
// V tile in 64 VGPRs (lane = f); weight tile through padded LDS.
// ---------------------------------------------------------------------------
__global__ __launch_bounds__(64) void attn_kernel(
    const float* __restrict__ el, const float* __restrict__ er,
    const float* __restrict__ mapped, const int* __restrict__ edges,
    float* __restrict__ attn)   // (B, N, H, F)
{
    const int lane = threadIdx.x;          // 0..63
    const int nt   = Nq / 16;              // 128 i-tiles
    const int bid  = blockIdx.x;           // 2*8*128 = 2048
    const int it   = bid % nt;
    const int h    = (bid / nt) % Hq;
    const int b    = bid / (nt * Hq);
    const int i0   = it * 16;

    __shared__ __align__(16) float w_s[16][68];   // stride 68: pad for b128 reads

    float el_r[16], m_r[16], l_r[16], acc[16];
#pragma unroll
    for (int r = 0; r < 16; r++) {
        el_r[r] = el[((size_t)b * Nq + i0 + r) * Hq + h];
        m_r[r]  = -INFINITY;
        l_r[r]  = 0.f;
        acc[r]  = 0.f;
    }

    const size_t edge_base = ((size_t)b * Nq + i0) * Nq;              // + r*N + j
    const size_t er_base   = (size_t)b * Nq * Hq + h;                 // + j*H
    const size_t v_base    = (((size_t)b * Nq) * Hq + h) * Fq + lane; // + j*H*F

    for (int j0 = 0; j0 < Nq; j0 += 64) {
        // er for this lane's j
        float er_j = er[er_base + (size_t)(j0 + lane) * Hq];
        // V tile into registers: V[j] = mapped[b, j0+j, h, lane]  (coalesced)
        float V[64];
#pragma unroll
        for (int j = 0; j < 64; j++)
            V[j] = mapped[v_base + (size_t)(j0 + j) * (Hq * Fq)];

        // scores + online softmax, row by row (lane = j)
#pragma unroll
        for (int r = 0; r < 16; r++) {
            int e = edges[edge_base + (size_t)r * Nq + j0 + lane];
            float s;
            if (e != 0) {
                float x = el_r[r] + er_j;
                s = x > 0.f ? x : NEG * x;
            } else {
                s = -INFINITY;
            }
            float mx = s;
#pragma unroll
            for (int off = 32; off > 0; off >>= 1)
                mx = fmaxf(mx, __shfl_xor(mx, off, 64));
            float mo = m_r[r];
            float mn = fmaxf(mo, mx);
            float alpha = (mo == -INFINITY) ? 0.f : __expf(mo - mn);
            float ev = (e != 0) ? __expf(s - mn) : 0.f;
            float sum = ev;
#pragma unroll
            for (int off = 32; off > 0; off >>= 1)
                sum += __shfl_xor(sum, off, 64);
            m_r[r] = mn;
            l_r[r] = l_r[r] * alpha + sum;
            acc[r] *= alpha;
            w_s[r][lane] = ev;
        }
        __syncthreads();

        // PV: acc[r] += sum_j w_s[r][j] * V[j]
#pragma unroll
        for (int r = 0; r < 16; r++) {
            float a0 = 0.f, a1 = 0.f, a2 = 0.f, a3 = 0.f;
#pragma unroll
            for (int j4 = 0; j4 < 16; j4++) {
                float4 w4 = *(const float4*)&w_s[r][j4 * 4];
                a0 += w4.x * V[j4 * 4 + 0];
                a1 += w4.y * V[j4 * 4 + 1];
                a2 += w4.z * V[j4 * 4 + 2];
                a3 += w4.w * V[j4 * 4 + 3];
            }
            acc[r] += (a0 + a1) + (a2 + a3);
        }
        __syncthreads();
    }

    // attn[b, i0+r, h, lane] = acc[r] / l[r]
#pragma unroll
    for (int r = 0; r < 16; r++)
        attn[(((size_t)b * Nq + i0 + r) * Hq + h) * Fq + lane] = acc[r] / l_r[r];
}

// ---------------------------------------------------------------------------
// Kernel 4: out[b,i,f] = sigmoid( (1/H) * sum_h attn[b,i,h,f] )
// ---------------------------------------------------------------------------
__global__ __launch_bounds__(256) void out_kernel(
    const float* __restrict__ attn, float* __restrict__ out)
{
    const int idx = blockIdx.x * 256 + threadIdx.x;   // 0..262143
    const int f   = idx & 63;
    const int bn  = idx >> 6;                          // b*N + i
    const float* p = attn + (size_t)bn * Hq * Fq + f;
    float s = 0.f;
#pragma unroll
    for (int h = 0; h < Hq; h++) s += p[h * Fq];
    s *= (1.f / Hq);
    out[idx] = 1.f / (1.f + __expf(-s));
}

// ---------------------------------------------------------------------------
extern "C" void kernel_launch(void* const* d_in, const int* in_sizes, int n_in,
                              void* d_out, int out_size, void* d_ws, size_t ws_size,
                              hipStream_t stream) {
    const float* nodes = (const float*)d_in[0];   // (2,2048,512)
    const int*   edges = (const int*)d_in[1];     // (2,2048,2048,1)
    const float* W     = (const float*)d_in[2];   // (512,512)
    const float* a     = (const float*)d_in[3];   // (128,)
    float* out = (float*)d_out;                   // (2,2048,64)

    float* ws     = (float*)d_ws;
    float* mapped = ws;                                   // 4,194,304 floats
    float* el     = mapped + (size_t)Bq * Nq * Hq * Fq;   //    32,768
    float* er     = el + (size_t)Bq * Nq * Hq;            //    32,768
    float* attn   = er + (size_t)Bq * Nq * Hq;            // 4,194,304

    gemm_kernel<<<dim3((Bq * Nq) / BM, (Hq * Fq) / BN), 256, 0, stream>>>(nodes, W, mapped);
    elr_kernel<<<(Bq * Nq * Hq * 64) / 256, 256, 0, stream>>>(mapped, a, el, er);
    attn_kernel<<<Bq * Hq * (Nq / 16), 64, 0, stream>>>(el, er, mapped, edges, attn);
    out_kernel<<<(Bq * Nq * Fq) / 256, 256, 0, stream>>>(attn, out);
}

// Round 2
// 389.453 us; speedup vs baseline: 2.5888x; 2.5888x over previous
//
#include <hip/hip_runtime.h>
#include <hip/hip_bf16.h>
#include <math.h>

// Problem constants (B, N, D_IN, H, F) = (2, 2048, 512, 8, 64)
#define Bq   2
#define Nq   2048
#define DIN  512
#define Hq   8
#define Fq   64
#define NEG  0.2f

// ---------------------------------------------------------------------------
// Kernel 1: mapped = nodes @ W   (4096 x 512) @ (512 x 512), fp32
// ---------------------------------------------------------------------------
#define BM 64
#define BN 64
#define BK 16

__global__ __launch_bounds__(256) void gemm_kernel(
    const float* __restrict__ A,   // nodes  (4096 x 512)
    const float* __restrict__ Bw,  // W      (512 x 512)
    float* __restrict__ C)         // mapped (4096 x 512)
{
    __shared__ __align__(16) float As[BK][BM + 4];
    __shared__ __align__(16) float Bs[BK][BN + 4];

    const int t  = threadIdx.x;
    const int m0 = blockIdx.x * BM;
    const int n0 = blockIdx.y * BN;
    const int tx = t % 16;
    const int ty = t / 16;

    const int lr   = t / 4;
    const int lc   = (t % 4) * 4;
    const int brow = t / 16;
    const int bcol = (t % 16) * 4;

    float acc[4][4];
#pragma unroll
    for (int i = 0; i < 4; i++)
#pragma unroll
        for (int j = 0; j < 4; j++) acc[i][j] = 0.f;

    for (int k0 = 0; k0 < DIN; k0 += BK) {
        float4 av = *(const float4*)&A[(size_t)(m0 + lr) * DIN + k0 + lc];
        float4 bv = *(const float4*)&Bw[(size_t)(k0 + brow) * (Hq * Fq) + n0 + bcol];
        __syncthreads();
        As[lc + 0][lr] = av.x;
        As[lc + 1][lr] = av.y;
        As[lc + 2][lr] = av.z;
        As[lc + 3][lr] = av.w;
        *(float4*)&Bs[brow][bcol] = bv;
        __syncthreads();
#pragma unroll
        for (int k = 0; k < BK; k++) {
            float4 a4 = *(const float4*)&As[k][ty * 4];
            float4 b4 = *(const float4*)&Bs[k][tx * 4];
            acc[0][0] += a4.x * b4.x; acc[0][1] += a4.x * b4.y; acc[0][2] += a4.x * b4.z; acc[0][3] += a4.x * b4.w;
            acc[1][0] += a4.y * b4.x; acc[1][1] += a4.y * b4.y; acc[1][2] += a4.y * b4.z; acc[1][3] += a4.y * b4.w;
            acc[2][0] += a4.z * b4.x; acc[2][1] += a4.z * b4.y; acc[2][2] += a4.z * b4.z; acc[2][3] += a4.z * b4.w;
            acc[3][0] += a4.w * b4.x; acc[3][1] += a4.w * b4.y; acc[3][2] += a4.w * b4.z; acc[3][3] += a4.w * b4.w;
        }
    }
#pragma unroll
    for (int i = 0; i < 4; i++) {
        float4 o = make_float4(acc[i][0], acc[i][1], acc[i][2], acc[i][3]);
        *(float4*)&C[(size_t)(m0 + ty * 4 + i) * (Hq * Fq) + n0 + tx * 4] = o;
    }
}

// ---------------------------------------------------------------------------
// Kernel 2: el_t[bh][n], er_t[bh][n] (TRANSPOSED layout for coalesced attn
// reads). One wave per (b, n, h).
// ---------------------------------------------------------------------------
__global__ __launch_bounds__(256) void elr_kernel(
    const float* __restrict__ mapped, const float* __restrict__ a,
    float* __restrict__ el_t, float* __restrict__ er_t)
{
    const int w    = (blockIdx.x * 256 + threadIdx.x) >> 6;   // b*N*H + n*H + h
    const int lane = threadIdx.x & 63;
    const int b = w / (Nq * Hq);
    const int n = (w / Hq) % Nq;
    const int h = w % Hq;
    float v  = mapped[(size_t)w * Fq + lane];
    float pl = v * a[lane];
    float pr = v * a[Fq + lane];
#pragma unroll
    for (int off = 32; off > 0; off >>= 1) {
        pl += __shfl_xor(pl, off, 64);
        pr += __shfl_xor(pr, off, 64);
    }
    if (lane == 0) {
        el_t[(size_t)(b * Hq + h) * Nq + n] = pl;
        er_t[(size_t)(b * Hq + h) * Nq + n] = pr;
    }
}

// ---------------------------------------------------------------------------
// Kernel 2b: ermax[bh] = max_n er_t[bh][n]   (16 blocks)
// ---------------------------------------------------------------------------
__global__ __launch_bounds__(256) void ermax_kernel(
    const float* __restrict__ er_t, float* __restrict__ ermax)
{
    const int bh = blockIdx.x;
    const int t  = threadIdx.x;
    float m = -INFINITY;
    for (int n = t; n < Nq; n += 256) m = fmaxf(m, er_t[(size_t)bh * Nq + n]);
#pragma unroll
    for (int off = 32; off > 0; off >>= 1) m = fmaxf(m, __shfl_xor(m, off, 64));
    __shared__ float sm[4];
    if ((t & 63) == 0) sm[t >> 6] = m;
    __syncthreads();
    if (t == 0) ermax[bh] = fmaxf(fmaxf(sm[0], sm[1]), fmaxf(sm[2], sm[3]));
}

// ---------------------------------------------------------------------------
// Kernel 3: one-pass masked attention (NO online softmax).
// Safe shift: m_r = lrelu(el_r + ermax[bh]) >= every masked score in row r.
// Block = 256 threads = 4 independent waves; wave handles RW=8 rows, all j.
// Per j-tile(64): weights lane=j -> LDS; PV lane=f with V in 64 VGPRs,
// broadcast ds_read_b128 of weights. l accumulated per-lane, reduced ONCE.
// ---------------------------------------------------------------------------
#define RW 8

__global__ __launch_bounds__(256) void attn_kernel(
    const float* __restrict__ el_t,   // (B*H, N)
    const float* __restrict__ er_t,   // (B*H, N)
    const float* __restrict__ ermax,  // (B*H)
    const float* __restrict__ mapped, // (B, N, H, F)
    const int*   __restrict__ edges,  // (B, N, N)
    float* __restrict__ attn)         // (B, N, H, F)
{
    const int lane = threadIdx.x & 63;
    const int wv   = threadIdx.x >> 6;          // 0..3
    const int nt   = Nq / 32;                   // 64 row-tiles of 32
    const int bid  = blockIdx.x;                // B*H*nt = 1024
    const int it   = bid % nt;
    const int h    = (bid / nt) % Hq;
    const int b    = bid / (nt * Hq);
    const int bh   = b * Hq + h;
    const int i0   = it * 32 + wv * RW;         // this wave's first row

    __shared__ __align__(16) float w_all[4][RW][68];
    float (*ws)[68] = w_all[wv];

    float el_r[RW], m_r[RW], l_lane[RW], acc[RW];
    const float emax = ermax[bh];
#pragma unroll
    for (int r = 0; r < RW; r++) {
        float e = el_t[(size_t)bh * Nq + i0 + r];
        float x = e + emax;
        el_r[r]   = e;
        m_r[r]    = fmaxf(x, NEG * x);   // lrelu, valid upper bound on row max
        l_lane[r] = 0.f;
        acc[r]    = 0.f;
    }

    const size_t edge_base = ((size_t)b * Nq + i0) * Nq;              // + r*N + j
    const size_t er_base   = (size_t)bh * Nq;                         // + j
    const size_t v_base    = (((size_t)b * Nq) * Hq + h) * Fq + lane; // + j*H*F

    for (int j0 = 0; j0 < Nq; j0 += 64) {
        float er_j = er_t[er_base + j0 + lane];          // coalesced
        float V[64];
#pragma unroll
        for (int j = 0; j < 64; j++)
            V[j] = mapped[v_base + (size_t)(j0 + j) * (Hq * Fq)];

        // weights: lane = j
#pragma unroll
        for (int r = 0; r < RW; r++) {
            int e = edges[edge_base + (size_t)r * Nq + j0 + lane];
            float x = el_r[r] + er_j;
            float s = fmaxf(x, NEG * x);
            float ev = (e != 0) ? __expf(s - m_r[r]) : 0.f;
            l_lane[r] += ev;
            ws[r][lane] = ev;
        }
        __syncthreads();   // own-wave LDS write->read visibility (cheap: all waves symmetric)

        // PV: lane = f; broadcast reads of ws
#pragma unroll
        for (int r = 0; r < RW; r++) {
            float a0 = 0.f, a1 = 0.f, a2 = 0.f, a3 = 0.f;
#pragma unroll
            for (int j4 = 0; j4 < 16; j4++) {
                float4 w4 = *(const float4*)&ws[r][j4 * 4];
                a0 += w4.x * V[j4 * 4 + 0];
                a1 += w4.y * V[j4 * 4 + 1];
                a2 += w4.z * V[j4 * 4 + 2];
                a3 += w4.w * V[j4 * 4 + 3];
            }
            acc[r] += (a0 + a1) + (a2 + a3);
        }
        __syncthreads();   // reads done before next tile's writes
    }

    // single final reduction of l over lanes, then write
#pragma unroll
    for (int r = 0; r < RW; r++) {
        float l = l_lane[r];
#pragma unroll
        for (int off = 32; off > 0; off >>= 1) l += __shfl_xor(l, off, 64);
        attn[(((size_t)b * Nq + i0 + r) * Hq + h) * Fq + lane] = acc[r] / l;
    }
}

// ---------------------------------------------------------------------------
// Kernel 4: out[b,i,f] = sigmoid( mean_h attn[b,i,h,f] )
// ---------------------------------------------------------------------------
__global__ __launch_bounds__(256) void out_kernel(
    const float* __restrict__ attn, float* __restrict__ out)
{
    const int idx = blockIdx.x * 256 + threadIdx.x;
    const int f   = idx & 63;
    const int bn  = idx >> 6;
    const float* p = attn + (size_t)bn * Hq * Fq + f;
    float s = 0.f;
#pragma unroll
    for (int h = 0; h < Hq; h++) s += p[h * Fq];
    s *= (1.f / Hq);
    out[idx] = 1.f / (1.f + __expf(-s));
}

// ---------------------------------------------------------------------------
extern "C" void kernel_launch(void* const* d_in, const int* in_sizes, int n_in,
                              void* d_out, int out_size, void* d_ws, size_t ws_size,
                              hipStream_t stream) {
    const float* nodes = (const float*)d_in[0];   // (2,2048,512)
    const int*   edges = (const int*)d_in[1];     // (2,2048,2048,1)
    const float* W     = (const float*)d_in[2];   // (512,512)
    const float* a     = (const float*)d_in[3];   // (128,)
    float* out = (float*)d_out;                   // (2,2048,64)

    float* ws     = (float*)d_ws;
    float* mapped = ws;                                   // 4,194,304 floats
    float* el_t   = mapped + (size_t)Bq * Nq * Hq * Fq;   //    32,768
    float* er_t   = el_t + (size_t)Bq * Nq * Hq;          //    32,768
    float* ermax  = er_t + (size_t)Bq * Nq * Hq;          //        16
    float* attn   = ermax + 16;                           // 4,194,304

    gemm_kernel<<<dim3((Bq * Nq) / BM, (Hq * Fq) / BN), 256, 0, stream>>>(nodes, W, mapped);
    elr_kernel<<<(Bq * Nq * Hq * 64) / 256, 256, 0, stream>>>(mapped, a, el_t, er_t);
    ermax_kernel<<<Bq * Hq, 256, 0, stream>>>(er_t, ermax);
    attn_kernel<<<Bq * Hq * (Nq / 32), 256, 0, stream>>>(el_t, er_t, ermax, mapped, edges, attn);
    out_kernel<<<(Bq * Nq * Fq) / 256, 256, 0, stream>>>(attn, out);
}

// Round 3
// 160.773 us; speedup vs baseline: 6.2710x; 2.4224x over previous
//
#include <hip/hip_runtime.h>
#include <hip/hip_bf16.h>
#include <math.h>

// Problem constants (B, N, D_IN, H, F) = (2, 2048, 512, 8, 64)
#define Bq   2
#define Nq   2048
#define DIN  512
#define Hq   8
#define Fq   64
#define NEG  0.2f

using short8 = __attribute__((ext_vector_type(8))) short;   // 8 bf16 (4 VGPRs)
using f32x4  = __attribute__((ext_vector_type(4))) float;   // MFMA C/D

__device__ inline unsigned int bf16_rne(float x) {
    unsigned int u = __float_as_uint(x);
    u += 0x7fffu + ((u >> 16) & 1u);
    return u >> 16;
}

// ---------------------------------------------------------------------------
// Kernel A: nodes fp32 -> bf16 (row-major [4096][512])
// ---------------------------------------------------------------------------
__global__ __launch_bounds__(256) void cvt_nodes_kernel(
    const float* __restrict__ in, ushort* __restrict__ out)
{
    int i = blockIdx.x * 256 + threadIdx.x;    // one float4 per thread
    float4 v = ((const float4*)in)[i];
    ushort4 o;
    o.x = (ushort)bf16_rne(v.x);
    o.y = (ushort)bf16_rne(v.y);
    o.z = (ushort)bf16_rne(v.z);
    o.w = (ushort)bf16_rne(v.w);
    ((ushort4*)out)[i] = o;
}

// ---------------------------------------------------------------------------
// Kernel B: W [k][n] fp32 -> Wt bf16 [n][k]  (512x512 transpose)
// ---------------------------------------------------------------------------
__global__ __launch_bounds__(256) void cvt_w_kernel(
    const float* __restrict__ W, ushort* __restrict__ Wt)
{
    __shared__ float tile[32][33];
    const int k0 = blockIdx.x * 32, n0 = blockIdx.y * 32;
    const int tx = threadIdx.x & 31, ty = threadIdx.x >> 5;   // 32 x 8
#pragma unroll
    for (int r = 0; r < 32; r += 8)
        tile[ty + r][tx] = W[(size_t)(k0 + ty + r) * (Hq * Fq) + n0 + tx];
    __syncthreads();
#pragma unroll
    for (int r = 0; r < 32; r += 8)
        Wt[(size_t)(n0 + ty + r) * DIN + k0 + tx] = (ushort)bf16_rne(tile[tx][ty + r]);
}

// ---------------------------------------------------------------------------
// Kernel C: pack edges (int 0/1) -> bitmask, 32 edges per uint32.
// ebit[(b*N+i)*64 + w] bit t = edges[b][i][w*32+t]
// ---------------------------------------------------------------------------
__global__ __launch_bounds__(256) void pack_edges_kernel(
    const int* __restrict__ edges, unsigned int* __restrict__ ebit)
{
    int gid = blockIdx.x * 256 + threadIdx.x;
    unsigned long long m = __ballot(edges[gid] != 0);
    int lane = threadIdx.x & 63;
    if (lane == 0)       ebit[gid >> 5] = (unsigned int)m;
    else if (lane == 32) ebit[gid >> 5] = (unsigned int)(m >> 32);
}

// ---------------------------------------------------------------------------
// Kernel D: MFMA GEMM  mapped = nodes_bf16 @ W  (4096x512 @ 512x512)
// Block: 256 thr (4 waves), covers 64 rows x one head (64 cols).
// Wave: 16 rows x 64 cols = 4 C-frags, K-loop 16 steps of 32.
// Epilogue: el/er (fused dot + shfl reduce) + Vfrag (bf16, B-fragment order).
// Vfrag[bh][s][nf][lane][jj]: lane=quad'*16+n', value = mapped[j=32s+8quad'+jj][h][16nf+n']
// ---------------------------------------------------------------------------
__global__ __launch_bounds__(256) void gemm_kernel(
    const ushort* __restrict__ A,    // nodes bf16 [4096][512]
    const ushort* __restrict__ Wt,   // [n=512][k=512] bf16
    const float*  __restrict__ avec, // a[128]
    ushort* __restrict__ Vfrag,      // [16][64][4][64][8] bf16
    float* __restrict__ el_t,        // [16][2048]
    float* __restrict__ er_t)        // [16][2048]
{
    const int lane = threadIdx.x & 63;
    const int wv   = threadIdx.x >> 6;
    const int quad = lane >> 4;
    const int l15  = lane & 15;
    const int h    = blockIdx.y;
    const int row0 = blockIdx.x * 64 + wv * 16;   // wave's first global row
    const int m_row = row0 + l15;

    const ushort* Aptr = A + (size_t)m_row * DIN + quad * 8;
    const ushort* Bptr = Wt + (size_t)(h * 64 + l15) * DIN + quad * 8;

    f32x4 zero4 = {0.f, 0.f, 0.f, 0.f};
    f32x4 acc[4] = {zero4, zero4, zero4, zero4};

    short8 a_cur = *(const short8*)(Aptr);
    short8 b_cur[4];
#pragma unroll
    for (int nf = 0; nf < 4; nf++)
        b_cur[nf] = *(const short8*)(Bptr + (size_t)nf * 16 * DIN);

    for (int ks = 0; ks < 16; ks++) {
        short8 a_nxt = a_cur, b_nxt[4];
#pragma unroll
        for (int nf = 0; nf < 4; nf++) b_nxt[nf] = b_cur[nf];
        if (ks < 15) {
            a_nxt = *(const short8*)(Aptr + (ks + 1) * 32);
#pragma unroll
            for (int nf = 0; nf < 4; nf++)
                b_nxt[nf] = *(const short8*)(Bptr + (size_t)nf * 16 * DIN + (ks + 1) * 32);
        }
#pragma unroll
        for (int nf = 0; nf < 4; nf++)
            acc[nf] = __builtin_amdgcn_mfma_f32_16x16x32_bf16(a_cur, b_cur[nf], acc[nf], 0, 0, 0);
        a_cur = a_nxt;
#pragma unroll
        for (int nf = 0; nf < 4; nf++) b_cur[nf] = b_nxt[nf];
    }

    // ---- fused el/er ----
    float aL[4], aR[4];
#pragma unroll
    for (int nf = 0; nf < 4; nf++) {
        aL[nf] = avec[nf * 16 + l15];
        aR[nf] = avec[Fq + nf * 16 + l15];
    }
    const int bb = row0 >> 11;           // batch index
    const int bh = bb * Hq + h;
#pragma unroll
    for (int r = 0; r < 4; r++) {
        float pl = acc[0][r] * aL[0] + acc[1][r] * aL[1] + acc[2][r] * aL[2] + acc[3][r] * aL[3];
        float pr = acc[0][r] * aR[0] + acc[1][r] * aR[1] + acc[2][r] * aR[2] + acc[3][r] * aR[3];
#pragma unroll
        for (int off = 1; off < 16; off <<= 1) {
            pl += __shfl_xor(pl, off, 64);
            pr += __shfl_xor(pr, off, 64);
        }
        if (l15 == 0) {
            int n = (row0 + quad * 4 + r) & (Nq - 1);
            el_t[(size_t)bh * Nq + n] = pl;
            er_t[(size_t)bh * Nq + n] = pr;
        }
    }

    // ---- Vfrag: write C in attn B-fragment order ----
    const int n_base = row0 & (Nq - 1);
    const int sblk   = n_base >> 5;                     // K-step this wave feeds
    const int quadp  = ((wv & 1) << 1) | (quad >> 1);   // k-quad within step
    const int jj0    = (quad & 1) * 4;                  // element offset
#pragma unroll
    for (int nf = 0; nf < 4; nf++) {
        unsigned int r0 = bf16_rne(acc[nf][0]), r1 = bf16_rne(acc[nf][1]);
        unsigned int r2 = bf16_rne(acc[nf][2]), r3 = bf16_rne(acc[nf][3]);
        uint2 pk;
        pk.x = r0 | (r1 << 16);
        pk.y = r2 | (r3 << 16);
        size_t off = ((((size_t)bh * 64 + sblk) * 4 + nf) * 64 + quadp * 16 + l15) * 8 + jj0;
        *(uint2*)(Vfrag + off) = pk;
    }
}

// ---------------------------------------------------------------------------
// Kernel E: ermax[bh] = max_n er_t[bh][n]
// ---------------------------------------------------------------------------
__global__ __launch_bounds__(256) void ermax_kernel(
    const float* __restrict__ er_t, float* __restrict__ ermax)
{
    const int bh = blockIdx.x;
    const int t  = threadIdx.x;
    float m = -INFINITY;
    for (int n = t; n < Nq; n += 256) m = fmaxf(m, er_t[(size_t)bh * Nq + n]);
#pragma unroll
    for (int off = 32; off > 0; off >>= 1) m = fmaxf(m, __shfl_xor(m, off, 64));
    __shared__ float sm[4];
    if ((t & 63) == 0) sm[t >> 6] = m;
    __syncthreads();
    if (t == 0) ermax[bh] = fmaxf(fmaxf(sm[0], sm[1]), fmaxf(sm[2], sm[3]));
}

// ---------------------------------------------------------------------------
// Kernel F: MFMA attention. Block 256 thr = 4 waves; wave = 16 rows x 64 f.
// A-frag (weights) computed in-register from el/er/edge bits; B-frag = Vfrag
// (coalesced dwordx4). l accumulated fp32 per lane, reduced once at end.
// ---------------------------------------------------------------------------
__global__ __launch_bounds__(256) void attn_kernel(
    const float* __restrict__ el_t, const float* __restrict__ er_t,
    const float* __restrict__ ermax, const ushort* __restrict__ Vfrag,
    const unsigned int* __restrict__ ebit, float* __restrict__ attn)
{
    const int lane = threadIdx.x & 63;
    const int wv   = threadIdx.x >> 6;
    const int quad = lane >> 4;
    const int l15  = lane & 15;
    const int bid  = blockIdx.x;          // 512 = B*H*32
    const int it   = bid & 31;
    const int h    = (bid >> 5) & 7;
    const int b    = bid >> 8;
    const int bh   = b * Hq + h;
    const int i0   = it * 64 + wv * 16;   // wave's first row (within batch)
    const int i_lane = i0 + l15;

    const float emax = ermax[bh];
    const float elv  = el_t[(size_t)bh * Nq + i_lane];
    const float xm   = elv + emax;
    const float mrow = fmaxf(xm, NEG * xm);   // safe shift: s - mrow <= 0

    const unsigned int* erow = ebit + ((size_t)b * Nq + i_lane) * 64;
    const ushort* vbase = Vfrag + (size_t)bh * 64 * 4 * 64 * 8;
    const float*  erp   = er_t + (size_t)bh * Nq;

    f32x4 zero4 = {0.f, 0.f, 0.f, 0.f};
    f32x4 acc[4] = {zero4, zero4, zero4, zero4};
    float l_lane = 0.f;

    short8 b_cur[4];
#pragma unroll
    for (int nf = 0; nf < 4; nf++)
        b_cur[nf] = *(const short8*)(vbase + ((size_t)nf * 64 + lane) * 8);
    unsigned int w_cur = erow[0];
    float4 e0_cur = *(const float4*)(erp + quad * 8);
    float4 e1_cur = *(const float4*)(erp + quad * 8 + 4);

    for (int s = 0; s < 64; s++) {
        short8 b_nxt[4];
#pragma unroll
        for (int nf = 0; nf < 4; nf++) b_nxt[nf] = b_cur[nf];
        unsigned int w_nxt = w_cur;
        float4 e0_n = e0_cur, e1_n = e1_cur;
        if (s < 63) {
#pragma unroll
            for (int nf = 0; nf < 4; nf++)
                b_nxt[nf] = *(const short8*)(vbase + (((size_t)(s + 1) * 4 + nf) * 64 + lane) * 8);
            w_nxt = erow[s + 1];
            e0_n = *(const float4*)(erp + (s + 1) * 32 + quad * 8);
            e1_n = *(const float4*)(erp + (s + 1) * 32 + quad * 8 + 4);
        }

        const unsigned int wq = w_cur >> (quad * 8);
        float er8[8] = {e0_cur.x, e0_cur.y, e0_cur.z, e0_cur.w,
                        e1_cur.x, e1_cur.y, e1_cur.z, e1_cur.w};
        unsigned int u[8];
#pragma unroll
        for (int jj = 0; jj < 8; jj++) {
            float x  = elv + er8[jj];
            float sc = fmaxf(x, NEG * x);
            float p  = __expf(sc - mrow);          // <= 1, no overflow
            float ev = ((wq >> jj) & 1u) ? p : 0.f;
            l_lane += ev;
            u[jj] = __float_as_uint(ev);
        }
        union { short8 s8; unsigned int w[4]; } af;
        af.w[0] = __builtin_amdgcn_perm(u[1], u[0], 0x07060302);
        af.w[1] = __builtin_amdgcn_perm(u[3], u[2], 0x07060302);
        af.w[2] = __builtin_amdgcn_perm(u[5], u[4], 0x07060302);
        af.w[3] = __builtin_amdgcn_perm(u[7], u[6], 0x07060302);

#pragma unroll
        for (int nf = 0; nf < 4; nf++)
            acc[nf] = __builtin_amdgcn_mfma_f32_16x16x32_bf16(af.s8, b_cur[nf], acc[nf], 0, 0, 0);

        w_cur = w_nxt; e0_cur = e0_n; e1_cur = e1_n;
#pragma unroll
        for (int nf = 0; nf < 4; nf++) b_cur[nf] = b_nxt[nf];
    }

    // row-sum l: rows live at lane&15, duplicated across quads with distinct j
    l_lane += __shfl_xor(l_lane, 16, 64);
    l_lane += __shfl_xor(l_lane, 32, 64);
    float lr[4];
#pragma unroll
    for (int r = 0; r < 4; r++) lr[r] = __shfl(l_lane, quad * 4 + r, 64);

#pragma unroll
    for (int nf = 0; nf < 4; nf++)
#pragma unroll
        for (int r = 0; r < 4; r++)
            attn[(((size_t)b * Nq + i0 + quad * 4 + r) * Hq + h) * Fq + nf * 16 + l15] =
                acc[nf][r] / lr[r];
}

// ---------------------------------------------------------------------------
// Kernel G: out[b,i,f] = sigmoid( mean_h attn[b,i,h,f] )
// ---------------------------------------------------------------------------
__global__ __launch_bounds__(256) void out_kernel(
    const float* __restrict__ attn, float* __restrict__ out)
{
    const int idx = blockIdx.x * 256 + threadIdx.x;
    const int f   = idx & 63;
    const int bn  = idx >> 6;
    const float* p = attn + (size_t)bn * Hq * Fq + f;
    float s = 0.f;
#pragma unroll
    for (int h = 0; h < Hq; h++) s += p[h * Fq];
    s *= (1.f / Hq);
    out[idx] = 1.f / (1.f + __expf(-s));
}

// ---------------------------------------------------------------------------
extern "C" void kernel_launch(void* const* d_in, const int* in_sizes, int n_in,
                              void* d_out, int out_size, void* d_ws, size_t ws_size,
                              hipStream_t stream) {
    const float* nodes = (const float*)d_in[0];   // (2,2048,512)
    const int*   edges = (const int*)d_in[1];     // (2,2048,2048,1)
    const float* W     = (const float*)d_in[2];   // (512,512)
    const float* a     = (const float*)d_in[3];   // (128,)
    float* out = (float*)d_out;                   // (2,2048,64)

    char* ws = (char*)d_ws;
    ushort* nodes_bf = (ushort*)ws;                       ws += (size_t)Bq * Nq * DIN * 2;      // 4 MB
    ushort* Wt       = (ushort*)ws;                       ws += (size_t)DIN * Hq * Fq * 2;      // 0.5 MB
    ushort* Vfrag    = (ushort*)ws;                       ws += (size_t)Bq * Hq * Nq * Fq * 2;  // 4 MB
    float*  el_t     = (float*)ws;                        ws += (size_t)Bq * Hq * Nq * 4;       // 128 KB
    float*  er_t     = (float*)ws;                        ws += (size_t)Bq * Hq * Nq * 4;       // 128 KB
    unsigned int* eb = (unsigned int*)ws;                 ws += (size_t)Bq * Nq * (Nq / 32) * 4;// 1 MB
    float*  ermax    = (float*)ws;                        ws += 256;
    float*  attn     = (float*)ws;                                                              // 16 MB

    cvt_nodes_kernel<<<(Bq * Nq * DIN / 4) / 256, 256, 0, stream>>>(nodes, nodes_bf);
    cvt_w_kernel<<<dim3(DIN / 32, (Hq * Fq) / 32), 256, 0, stream>>>(W, Wt);
    pack_edges_kernel<<<((size_t)Bq * Nq * Nq) / 256, 256, 0, stream>>>(edges, eb);
    gemm_kernel<<<dim3((Bq * Nq) / 64, Hq), 256, 0, stream>>>(nodes_bf, Wt, a, Vfrag, el_t, er_t);
    ermax_kernel<<<Bq * Hq, 256, 0, stream>>>(er_t, ermax);
    attn_kernel<<<Bq * Hq * (Nq / 64), 256, 0, stream>>>(el_t, er_t, ermax, Vfrag, eb, attn);
    out_kernel<<<(Bq * Nq * Fq) / 256, 256, 0, stream>>>(attn, out);
}

// Round 4
// 159.098 us; speedup vs baseline: 6.3370x; 1.0105x over previous
//
#include <hip/hip_runtime.h>
#include <hip/hip_bf16.h>
#include <math.h>

// Problem constants (B, N, D_IN, H, F) = (2, 2048, 512, 8, 64)
#define Bq   2
#define Nq   2048
#define DIN  512
#define Hq   8
#define Fq   64
#define NEG  0.2f

using short8 = __attribute__((ext_vector_type(8))) short;   // 8 bf16 (4 VGPRs)
using f32x4  = __attribute__((ext_vector_type(4))) float;   // MFMA C/D

__device__ inline unsigned int bf16_rne(float x) {
    unsigned int u = __float_as_uint(x);
    u += 0x7fffu + ((u >> 16) & 1u);
    return u >> 16;
}

// ---------------------------------------------------------------------------
// Kernel A: pack nodes fp32 -> Afrag bf16 in MFMA A-fragment order.
// Afrag[(mt*16+ks)*64 + lane] octet jj = A[mt*16 + (lane&15)][ks*32 + (lane>>4)*8 + jj]
// One block per 16-row tile mt (256 blocks). LDS transpose, padded stride.
// ---------------------------------------------------------------------------
__global__ __launch_bounds__(256) void afrag_kernel(
    const float* __restrict__ nodes, ushort* __restrict__ Afrag)
{
    __shared__ __align__(16) float As[16][516];
    const int mt = blockIdx.x;
    const int t  = threadIdx.x;
    {
        const int row = t >> 4, c = t & 15;
#pragma unroll
        for (int i = 0; i < 8; i++) {
            float4 v = *(const float4*)&nodes[((size_t)mt * 16 + row) * DIN + (c + i * 16) * 4];
            *(float4*)&As[row][(c + i * 16) * 4] = v;
        }
    }
    __syncthreads();
    const int lane = t & 63, ksg = t >> 6;
    const int quad = lane >> 4, l15 = lane & 15;
#pragma unroll
    for (int k2 = 0; k2 < 4; k2++) {
        int ks = ksg * 4 + k2;
        const float* src = &As[l15][ks * 32 + quad * 8];
        float4 f0 = *(const float4*)src;
        float4 f1 = *(const float4*)(src + 4);
        uint4 pk;
        pk.x = bf16_rne(f0.x) | (bf16_rne(f0.y) << 16);
        pk.y = bf16_rne(f0.z) | (bf16_rne(f0.w) << 16);
        pk.z = bf16_rne(f1.x) | (bf16_rne(f1.y) << 16);
        pk.w = bf16_rne(f1.z) | (bf16_rne(f1.w) << 16);
        *(uint4*)(Afrag + ((size_t)(mt * 16 + ks) * 64 + lane) * 8) = pk;
    }
}

// ---------------------------------------------------------------------------
// Kernel B: pack W fp32 [k][n] -> Wfrag bf16 in MFMA B-fragment order.
// Wfrag[((h*16+ks)*4+nf)*64 + lane] octet jj = W[ks*32 + (lane>>4)*8 + jj][h*64 + nf*16 + (lane&15)]
// Grid (ks=16, h=8).
// ---------------------------------------------------------------------------
__global__ __launch_bounds__(256) void wfrag_kernel(
    const float* __restrict__ W, ushort* __restrict__ Wfrag)
{
    __shared__ __align__(16) float Ws[32][68];
    const int ks = blockIdx.x, h = blockIdx.y;
    const int t  = threadIdx.x;
    {
        const int row = t >> 3, c = t & 7;
        const float* src = &W[(size_t)(ks * 32 + row) * (Hq * Fq) + h * 64 + c * 8];
        float4 v0 = *(const float4*)src;
        float4 v1 = *(const float4*)(src + 4);
        *(float4*)&Ws[row][c * 8]     = v0;
        *(float4*)&Ws[row][c * 8 + 4] = v1;
    }
    __syncthreads();
    const int lane = t & 63, nf = t >> 6;
    const int quad = lane >> 4, l15 = lane & 15;
    float f[8];
#pragma unroll
    for (int jj = 0; jj < 8; jj++) f[jj] = Ws[quad * 8 + jj][nf * 16 + l15];
    uint4 pk;
    pk.x = bf16_rne(f[0]) | (bf16_rne(f[1]) << 16);
    pk.y = bf16_rne(f[2]) | (bf16_rne(f[3]) << 16);
    pk.z = bf16_rne(f[4]) | (bf16_rne(f[5]) << 16);
    pk.w = bf16_rne(f[6]) | (bf16_rne(f[7]) << 16);
    *(uint4*)(Wfrag + (((size_t)(h * 16 + ks) * 4 + nf) * 64 + lane) * 8) = pk;
}

// ---------------------------------------------------------------------------
// Kernel C: pack edges -> TRANSPOSED bitmask ebT[b][jword(64)][i(2048)].
// bit t of ebT[b][w][i] = edges[b][i][w*32+t]. Coalesced reads in attn.
// ---------------------------------------------------------------------------
__global__ __launch_bounds__(256) void pack_edges_kernel(
    const int* __restrict__ edges, unsigned int* __restrict__ ebT)
{
    int gid = blockIdx.x * 256 + threadIdx.x;
    unsigned long long m = __ballot(edges[gid] != 0);
    int lane = threadIdx.x & 63;
    int b = gid >> 22;
    int i = (gid >> 11) & 2047;
    int j = gid & 2047;
    if (lane == 0)
        ebT[((size_t)b * 64 + (j >> 5)) * Nq + i] = (unsigned int)m;
    else if (lane == 32)
        ebT[((size_t)b * 64 + (j >> 5)) * Nq + i] = (unsigned int)(m >> 32);
}

// ---------------------------------------------------------------------------
// Kernel D: MFMA GEMM from fragments, all loads coalesced dwordx4.
// Grid (B*N/64, H); 4 waves; wave = 16 rows x 64 cols, K ping-pong.
// Epilogue: fused el/er + Vfrag (attn B-fragment order) — as validated in R3.
// ---------------------------------------------------------------------------
__global__ __launch_bounds__(256) void gemm_kernel(
    const ushort* __restrict__ Afrag, const ushort* __restrict__ Wfrag,
    const float*  __restrict__ avec,
    ushort* __restrict__ Vfrag,      // [16 bh][64 s][4 nf][64 lane][8] bf16
    float* __restrict__ el_t,        // [16][2048]
    float* __restrict__ er_t)        // [16][2048]
{
    const int lane = threadIdx.x & 63;
    const int wv   = threadIdx.x >> 6;
    const int quad = lane >> 4;
    const int l15  = lane & 15;
    const int h    = blockIdx.y;
    const int mt   = blockIdx.x * 4 + wv;
    const int row0 = mt * 16;

    const ushort* ap = Afrag + (size_t)mt * 8192 + lane * 8;            // + ks*512
    const ushort* bp = Wfrag + (size_t)h * 32768 + lane * 8;            // + ks*2048 + nf*512

    f32x4 zero4 = {0.f, 0.f, 0.f, 0.f};
    f32x4 acc[4] = {zero4, zero4, zero4, zero4};

    short8 a0, a1, b0[4], b1[4];
    a0 = *(const short8*)(ap);
#pragma unroll
    for (int nf = 0; nf < 4; nf++) b0[nf] = *(const short8*)(bp + nf * 512);

    for (int ks = 0; ks < 16; ks += 2) {
        a1 = *(const short8*)(ap + (ks + 1) * 512);
#pragma unroll
        for (int nf = 0; nf < 4; nf++) b1[nf] = *(const short8*)(bp + (ks + 1) * 2048 + nf * 512);
#pragma unroll
        for (int nf = 0; nf < 4; nf++)
            acc[nf] = __builtin_amdgcn_mfma_f32_16x16x32_bf16(a0, b0[nf], acc[nf], 0, 0, 0);
        a0 = *(const short8*)(ap + (ks + 2) * 512);   // ks=14 -> 16: lands in Wfrag, unused
#pragma unroll
        for (int nf = 0; nf < 4; nf++) b0[nf] = *(const short8*)(bp + (ks + 2) * 2048 + nf * 512);
#pragma unroll
        for (int nf = 0; nf < 4; nf++)
            acc[nf] = __builtin_amdgcn_mfma_f32_16x16x32_bf16(a1, b1[nf], acc[nf], 0, 0, 0);
    }

    // ---- fused el/er ----
    float aL[4], aR[4];
#pragma unroll
    for (int nf = 0; nf < 4; nf++) {
        aL[nf] = avec[nf * 16 + l15];
        aR[nf] = avec[Fq + nf * 16 + l15];
    }
    const int bb = row0 >> 11;
    const int bh = bb * Hq + h;
#pragma unroll
    for (int r = 0; r < 4; r++) {
        float pl = acc[0][r] * aL[0] + acc[1][r] * aL[1] + acc[2][r] * aL[2] + acc[3][r] * aL[3];
        float pr = acc[0][r] * aR[0] + acc[1][r] * aR[1] + acc[2][r] * aR[2] + acc[3][r] * aR[3];
#pragma unroll
        for (int off = 1; off < 16; off <<= 1) {
            pl += __shfl_xor(pl, off, 64);
            pr += __shfl_xor(pr, off, 64);
        }
        if (l15 == 0) {
            int n = (row0 + quad * 4 + r) & (Nq - 1);
            el_t[(size_t)bh * Nq + n] = pl;
            er_t[(size_t)bh * Nq + n] = pr;
        }
    }

    // ---- Vfrag: C in attn B-fragment order (validated R3) ----
    const int n_base = row0 & (Nq - 1);
    const int sblk   = n_base >> 5;
    const int quadp  = ((wv & 1) << 1) | (quad >> 1);
    const int jj0    = (quad & 1) * 4;
#pragma unroll
    for (int nf = 0; nf < 4; nf++) {
        unsigned int r0 = bf16_rne(acc[nf][0]), r1 = bf16_rne(acc[nf][1]);
        unsigned int r2 = bf16_rne(acc[nf][2]), r3 = bf16_rne(acc[nf][3]);
        uint2 pk;
        pk.x = r0 | (r1 << 16);
        pk.y = r2 | (r3 << 16);
        size_t off = ((((size_t)bh * 64 + sblk) * 4 + nf) * 64 + quadp * 16 + l15) * 8 + jj0;
        *(uint2*)(Vfrag + off) = pk;
    }
}

// ---------------------------------------------------------------------------
// Kernel E: ermax[bh] = max_n er_t[bh][n]
// ---------------------------------------------------------------------------
__global__ __launch_bounds__(256) void ermax_kernel(
    const float* __restrict__ er_t, float* __restrict__ ermax)
{
    const int bh = blockIdx.x;
    const int t  = threadIdx.x;
    float m = -INFINITY;
    for (int n = t; n < Nq; n += 256) m = fmaxf(m, er_t[(size_t)bh * Nq + n]);
#pragma unroll
    for (int off = 32; off > 0; off >>= 1) m = fmaxf(m, __shfl_xor(m, off, 64));
    __shared__ float sm[4];
    if ((t & 63) == 0) sm[t >> 6] = m;
    __syncthreads();
    if (t == 0) ermax[bh] = fmaxf(fmaxf(sm[0], sm[1]), fmaxf(sm[2], sm[3]));
}

// ---------------------------------------------------------------------------
// Kernel F: MFMA attention, K-split 4.
// Block 256 thr = 4 waves, all on the SAME 32-row i-tile; wave kh handles
// j in [kh*512, kh*512+512) (16 K-steps). Two A-frags (rows i0..15, i0+16..31)
// share the B-frags -> half the Vfrag traffic. LDS combine, wave 0 writes.
// ---------------------------------------------------------------------------
__global__ __launch_bounds__(256, 4) void attn_kernel(
    const float* __restrict__ el_t, const float* __restrict__ er_t,
    const float* __restrict__ ermax, const ushort* __restrict__ Vfrag,
    const unsigned int* __restrict__ ebT, float* __restrict__ attn)
{
    const int lane = threadIdx.x & 63;
    const int kh   = threadIdx.x >> 6;     // K-split index 0..3
    const int quad = lane >> 4;
    const int l15  = lane & 15;
    const int bid  = blockIdx.x;           // B*H*64 = 1024
    const int it   = bid & 63;
    const int h    = (bid >> 6) & 7;
    const int b    = bid >> 9;
    const int bh   = b * Hq + h;
    const int i0   = it * 32;

    const float emax = ermax[bh];
    const float elv0 = el_t[(size_t)bh * Nq + i0 + l15];
    const float elv1 = el_t[(size_t)bh * Nq + i0 + 16 + l15];
    float xm0 = elv0 + emax, xm1 = elv1 + emax;
    const float m0 = fmaxf(xm0, NEG * xm0);
    const float m1 = fmaxf(xm1, NEG * xm1);
    const float c1_0 = elv0 - m0, c2_0 = NEG * elv0 - m0;
    const float c1_1 = elv1 - m1, c2_1 = NEG * elv1 - m1;

    const float*        erp = er_t + (size_t)bh * Nq + kh * 512;        // + s*32
    const ushort*       vp  = Vfrag + (size_t)bh * 131072 + kh * 32768; // + s*2048
    const unsigned int* e0p = ebT + ((size_t)b * 64 + kh * 16) * Nq + i0 + l15;  // + s*2048
    const unsigned int* e1p = e0p + 16;

    f32x4 zero4 = {0.f, 0.f, 0.f, 0.f};
    f32x4 acc0[4] = {zero4, zero4, zero4, zero4};
    f32x4 acc1[4] = {zero4, zero4, zero4, zero4};
    float l0 = 0.f, l1 = 0.f;

    short8 vb[2][4];
    unsigned int w0[2], w1[2];
    float4 ea[2], eb[2];

#define LOADS(s, p)                                                           \
    {                                                                         \
        _Pragma("unroll")                                                     \
        for (int nf = 0; nf < 4; nf++)                                        \
            vb[p][nf] = *(const short8*)(vp + (s) * 2048 + nf * 512 + lane * 8); \
        w0[p] = e0p[(size_t)(s) * Nq];                                        \
        w1[p] = e1p[(size_t)(s) * Nq];                                        \
        ea[p] = *(const float4*)(erp + (s) * 32 + quad * 8);                  \
        eb[p] = *(const float4*)(erp + (s) * 32 + quad * 8 + 4);              \
    }

#define COMPUTE(p)                                                            \
    {                                                                         \
        unsigned int wq0 = w0[p] >> (quad * 8);                               \
        unsigned int wq1 = w1[p] >> (quad * 8);                               \
        float er8[8] = {ea[p].x, ea[p].y, ea[p].z, ea[p].w,                   \
                        eb[p].x, eb[p].y, eb[p].z, eb[p].w};                  \
        unsigned int u0[8], u1[8];                                            \
        _Pragma("unroll")                                                     \
        for (int jj = 0; jj < 8; jj++) {                                      \
            float e  = er8[jj];                                               \
            float t0 = fmaxf(e + c1_0, fmaf(NEG, e, c2_0));                   \
            float t1 = fmaxf(e + c1_1, fmaf(NEG, e, c2_1));                   \
            float x0 = __expf(t0);                                            \
            float x1 = __expf(t1);                                            \
            int k0 = ((int)(wq0 << (31 - jj))) >> 31;                         \
            int k1 = ((int)(wq1 << (31 - jj))) >> 31;                         \
            u0[jj] = __float_as_uint(x0) & (unsigned int)k0;                  \
            u1[jj] = __float_as_uint(x1) & (unsigned int)k1;                  \
        }                                                                     \
        l0 += ((__uint_as_float(u0[0]) + __uint_as_float(u0[1])) +            \
               (__uint_as_float(u0[2]) + __uint_as_float(u0[3]))) +           \
              ((__uint_as_float(u0[4]) + __uint_as_float(u0[5])) +            \
               (__uint_as_float(u0[6]) + __uint_as_float(u0[7])));            \
        l1 += ((__uint_as_float(u1[0]) + __uint_as_float(u1[1])) +            \
               (__uint_as_float(u1[2]) + __uint_as_float(u1[3]))) +           \
              ((__uint_as_float(u1[4]) + __uint_as_float(u1[5])) +            \
               (__uint_as_float(u1[6]) + __uint_as_float(u1[7])));            \
        union { short8 s8; unsigned int w[4]; } af0, af1;                     \
        af0.w[0] = __builtin_amdgcn_perm(u0[1], u0[0], 0x07060302);           \
        af0.w[1] = __builtin_amdgcn_perm(u0[3], u0[2], 0x07060302);           \
        af0.w[2] = __builtin_amdgcn_perm(u0[5], u0[4], 0x07060302);           \
        af0.w[3] = __builtin_amdgcn_perm(u0[7], u0[6], 0x07060302);           \
        af1.w[0] = __builtin_amdgcn_perm(u1[1], u1[0], 0x07060302);           \
        af1.w[1] = __builtin_amdgcn_perm(u1[3], u1[2], 0x07060302);           \
        af1.w[2] = __builtin_amdgcn_perm(u1[5], u1[4], 0x07060302);           \
        af1.w[3] = __builtin_amdgcn_perm(u1[7], u1[6], 0x07060302);           \
        _Pragma("unroll")                                                     \
        for (int nf = 0; nf < 4; nf++) {                                      \
            acc0[nf] = __builtin_amdgcn_mfma_f32_16x16x32_bf16(af0.s8, vb[p][nf], acc0[nf], 0, 0, 0); \
            acc1[nf] = __builtin_amdgcn_mfma_f32_16x16x32_bf16(af1.s8, vb[p][nf], acc1[nf], 0, 0, 0); \
        }                                                                     \
    }

    LOADS(0, 0);
    for (int s = 0; s < 16; s += 2) {
        LOADS(s + 1, 1);
        COMPUTE(0);
        LOADS(s + 2, 0);     // s=14 -> 16: one step past; lands in valid ws, unused
        COMPUTE(1);
    }
#undef LOADS
#undef COMPUTE

    // ---- combine 4 K-splits via LDS ----
    __shared__ float lds_acc[3][32][64];
    __shared__ float lds_l[3][2][64];
    if (kh > 0) {
#pragma unroll
        for (int nf = 0; nf < 4; nf++)
#pragma unroll
            for (int r = 0; r < 4; r++) {
                lds_acc[kh - 1][nf * 4 + r][lane]      = acc0[nf][r];
                lds_acc[kh - 1][16 + nf * 4 + r][lane] = acc1[nf][r];
            }
        lds_l[kh - 1][0][lane] = l0;
        lds_l[kh - 1][1][lane] = l1;
    }
    __syncthreads();
    if (kh == 0) {
#pragma unroll
        for (int q = 0; q < 3; q++) {
#pragma unroll
            for (int nf = 0; nf < 4; nf++)
#pragma unroll
                for (int r = 0; r < 4; r++) {
                    acc0[nf][r] += lds_acc[q][nf * 4 + r][lane];
                    acc1[nf][r] += lds_acc[q][16 + nf * 4 + r][lane];
                }
            l0 += lds_l[q][0][lane];
            l1 += lds_l[q][1][lane];
        }
        l0 += __shfl_xor(l0, 16, 64);
        l0 += __shfl_xor(l0, 32, 64);
        l1 += __shfl_xor(l1, 16, 64);
        l1 += __shfl_xor(l1, 32, 64);
        float lr0[4], lr1[4];
#pragma unroll
        for (int r = 0; r < 4; r++) {
            lr0[r] = __shfl(l0, quad * 4 + r, 64);
            lr1[r] = __shfl(l1, quad * 4 + r, 64);
        }
#pragma unroll
        for (int nf = 0; nf < 4; nf++)
#pragma unroll
            for (int r = 0; r < 4; r++) {
                attn[(((size_t)b * Nq + i0 + quad * 4 + r) * Hq + h) * Fq + nf * 16 + l15] =
                    acc0[nf][r] / lr0[r];
                attn[(((size_t)b * Nq + i0 + 16 + quad * 4 + r) * Hq + h) * Fq + nf * 16 + l15] =
                    acc1[nf][r] / lr1[r];
            }
    }
}

// ---------------------------------------------------------------------------
// Kernel G: out[b,i,f] = sigmoid( mean_h attn[b,i,h,f] )
// ---------------------------------------------------------------------------
__global__ __launch_bounds__(256) void out_kernel(
    const float* __restrict__ attn, float* __restrict__ out)
{
    const int idx = blockIdx.x * 256 + threadIdx.x;
    const int f   = idx & 63;
    const int bn  = idx >> 6;
    const float* p = attn + (size_t)bn * Hq * Fq + f;
    float s = 0.f;
#pragma unroll
    for (int h = 0; h < Hq; h++) s += p[h * Fq];
    s *= (1.f / Hq);
    out[idx] = 1.f / (1.f + __expf(-s));
}

// ---------------------------------------------------------------------------
extern "C" void kernel_launch(void* const* d_in, const int* in_sizes, int n_in,
                              void* d_out, int out_size, void* d_ws, size_t ws_size,
                              hipStream_t stream) {
    const float* nodes = (const float*)d_in[0];   // (2,2048,512)
    const int*   edges = (const int*)d_in[1];     // (2,2048,2048,1)
    const float* W     = (const float*)d_in[2];   // (512,512)
    const float* a     = (const float*)d_in[3];   // (128,)
    float* out = (float*)d_out;                   // (2,2048,64)

    char* ws = (char*)d_ws;
    ushort* Afrag = (ushort*)ws;        ws += (size_t)Bq * Nq * DIN * 2;           // 4 MB
    ushort* Wfrag = (ushort*)ws;        ws += (size_t)DIN * Hq * Fq * 2;           // 512 KB
    ushort* Vfrag = (ushort*)ws;        ws += (size_t)Bq * Hq * Nq * Fq * 2;       // 4 MB
    float*  el_t  = (float*)ws;         ws += (size_t)Bq * Hq * Nq * 4;            // 128 KB
    float*  er_t  = (float*)ws;         ws += (size_t)Bq * Hq * Nq * 4;            // 128 KB
    unsigned int* ebT = (unsigned int*)ws; ws += (size_t)Bq * (Nq / 32) * Nq * 4;  // 1 MB
    float*  ermax = (float*)ws;         ws += 1024;
    float*  attn  = (float*)ws;                                                    // 16 MB

    afrag_kernel<<<(Bq * Nq) / 16, 256, 0, stream>>>(nodes, Afrag);
    wfrag_kernel<<<dim3(DIN / 32, Hq), 256, 0, stream>>>(W, Wfrag);
    pack_edges_kernel<<<((size_t)Bq * Nq * Nq) / 256, 256, 0, stream>>>(edges, ebT);
    gemm_kernel<<<dim3((Bq * Nq) / 64, Hq), 256, 0, stream>>>(Afrag, Wfrag, a, Vfrag, el_t, er_t);
    ermax_kernel<<<Bq * Hq, 256, 0, stream>>>(er_t, ermax);
    attn_kernel<<<Bq * Hq * (Nq / 32), 256, 0, stream>>>(el_t, er_t, ermax, Vfrag, ebT, attn);
    out_kernel<<<(Bq * Nq * Fq) / 256, 256, 0, stream>>>(attn, out);
}

// Round 7
// 128.394 us; speedup vs baseline: 7.8525x; 1.2391x over previous
//
#include <hip/hip_runtime.h>
#include <hip/hip_bf16.h>
#include <math.h>

// Problem constants (B, N, D_IN, H, F) = (2, 2048, 512, 8, 64)
#define Bq   2
#define Nq   2048
#define DIN  512
#define Hq   8
#define Fq   64
#define NEG  0.2f

using short8 = __attribute__((ext_vector_type(8))) short;   // 8 bf16 (4 VGPRs)
using f32x4  = __attribute__((ext_vector_type(4))) float;   // MFMA C/D

__device__ inline unsigned int bf16_rne(float x) {
    unsigned int u = __float_as_uint(x);
    u += 0x7fffu + ((u >> 16) & 1u);
    return u >> 16;
}

// ---------------------------------------------------------------------------
// Kernel A: pack nodes fp32 -> Afrag bf16 in MFMA A-fragment order. (R4-validated)
// Afrag[(mt*16+ks)*64 + lane] octet jj = A[mt*16 + (lane&15)][ks*32 + (lane>>4)*8 + jj]
// ---------------------------------------------------------------------------
__global__ __launch_bounds__(256) void afrag_kernel(
    const float* __restrict__ nodes, ushort* __restrict__ Afrag)
{
    __shared__ __align__(16) float As[16][516];
    const int mt = blockIdx.x;
    const int t  = threadIdx.x;
    {
        const int row = t >> 4, c = t & 15;
#pragma unroll
        for (int i = 0; i < 8; i++) {
            float4 v = *(const float4*)&nodes[((size_t)mt * 16 + row) * DIN + (c + i * 16) * 4];
            *(float4*)&As[row][(c + i * 16) * 4] = v;
        }
    }
    __syncthreads();
    const int lane = t & 63, ksg = t >> 6;
    const int quad = lane >> 4, l15 = lane & 15;
#pragma unroll
    for (int k2 = 0; k2 < 4; k2++) {
        int ks = ksg * 4 + k2;
        const float* src = &As[l15][ks * 32 + quad * 8];
        float4 f0 = *(const float4*)src;
        float4 f1 = *(const float4*)(src + 4);
        uint4 pk;
        pk.x = bf16_rne(f0.x) | (bf16_rne(f0.y) << 16);
        pk.y = bf16_rne(f0.z) | (bf16_rne(f0.w) << 16);
        pk.z = bf16_rne(f1.x) | (bf16_rne(f1.y) << 16);
        pk.w = bf16_rne(f1.z) | (bf16_rne(f1.w) << 16);
        *(uint4*)(Afrag + ((size_t)(mt * 16 + ks) * 64 + lane) * 8) = pk;
    }
}

// ---------------------------------------------------------------------------
// Kernel B: pack W fp32 [k][n] -> Wfrag bf16 in MFMA B-fragment order. (R4-validated)
// ---------------------------------------------------------------------------
__global__ __launch_bounds__(256) void wfrag_kernel(
    const float* __restrict__ W, ushort* __restrict__ Wfrag)
{
    __shared__ __align__(16) float Ws[32][68];
    const int ks = blockIdx.x, h = blockIdx.y;
    const int t  = threadIdx.x;
    {
        const int row = t >> 3, c = t & 7;
        const float* src = &W[(size_t)(ks * 32 + row) * (Hq * Fq) + h * 64 + c * 8];
        float4 v0 = *(const float4*)src;
        float4 v1 = *(const float4*)(src + 4);
        *(float4*)&Ws[row][c * 8]     = v0;
        *(float4*)&Ws[row][c * 8 + 4] = v1;
    }
    __syncthreads();
    const int lane = t & 63, nf = t >> 6;
    const int quad = lane >> 4, l15 = lane & 15;
    float f[8];
#pragma unroll
    for (int jj = 0; jj < 8; jj++) f[jj] = Ws[quad * 8 + jj][nf * 16 + l15];
    uint4 pk;
    pk.x = bf16_rne(f[0]) | (bf16_rne(f[1]) << 16);
    pk.y = bf16_rne(f[2]) | (bf16_rne(f[3]) << 16);
    pk.z = bf16_rne(f[4]) | (bf16_rne(f[5]) << 16);
    pk.w = bf16_rne(f[6]) | (bf16_rne(f[7]) << 16);
    *(uint4*)(Wfrag + (((size_t)(h * 16 + ks) * 4 + nf) * 64 + lane) * 8) = pk;
}

// ---------------------------------------------------------------------------
// Kernel C: pack edges -> TRANSPOSED bitmask ebT[b][jword(64)][i(2048)]. (R4-validated)
// ---------------------------------------------------------------------------
__global__ __launch_bounds__(256) void pack_edges_kernel(
    const int* __restrict__ edges, unsigned int* __restrict__ ebT)
{
    int gid = blockIdx.x * 256 + threadIdx.x;
    unsigned long long m = __ballot(edges[gid] != 0);
    int lane = threadIdx.x & 63;
    int b = gid >> 22;
    int i = (gid >> 11) & 2047;
    int j = gid & 2047;
    if (lane == 0)
        ebT[((size_t)b * 64 + (j >> 5)) * Nq + i] = (unsigned int)m;
    else if (lane == 32)
        ebT[((size_t)b * 64 + (j >> 5)) * Nq + i] = (unsigned int)(m >> 32);
}

// ---------------------------------------------------------------------------
// Kernel D: MFMA GEMM from fragments (R4-validated), all loads coalesced.
// Epilogue: fused el/er + Vfrag (attn B-fragment order).
// ---------------------------------------------------------------------------
__global__ __launch_bounds__(256) void gemm_kernel(
    const ushort* __restrict__ Afrag, const ushort* __restrict__ Wfrag,
    const float*  __restrict__ avec,
    ushort* __restrict__ Vfrag,      // [16 bh][64 s][4 nf][64 lane][8] bf16
    float* __restrict__ el_t,        // [16][2048]
    float* __restrict__ er_t)        // [16][2048]
{
    const int lane = threadIdx.x & 63;
    const int wv   = threadIdx.x >> 6;
    const int quad = lane >> 4;
    const int l15  = lane & 15;
    const int h    = blockIdx.y;
    const int mt   = blockIdx.x * 4 + wv;
    const int row0 = mt * 16;

    const ushort* ap = Afrag + (size_t)mt * 8192 + lane * 8;   // + ks*512
    const ushort* bp = Wfrag + (size_t)h * 32768 + lane * 8;   // + ks*2048 + nf*512

    f32x4 zero4 = {0.f, 0.f, 0.f, 0.f};
    f32x4 acc[4] = {zero4, zero4, zero4, zero4};

    short8 a0, a1, b0[4], b1[4];
    a0 = *(const short8*)(ap);
#pragma unroll
    for (int nf = 0; nf < 4; nf++) b0[nf] = *(const short8*)(bp + nf * 512);

    for (int ks = 0; ks < 16; ks += 2) {
        a1 = *(const short8*)(ap + (ks + 1) * 512);
#pragma unroll
        for (int nf = 0; nf < 4; nf++) b1[nf] = *(const short8*)(bp + (ks + 1) * 2048 + nf * 512);
#pragma unroll
        for (int nf = 0; nf < 4; nf++)
            acc[nf] = __builtin_amdgcn_mfma_f32_16x16x32_bf16(a0, b0[nf], acc[nf], 0, 0, 0);
        a0 = *(const short8*)(ap + (ks + 2) * 512);   // ks=14 -> past end: lands in Wfrag, unused
#pragma unroll
        for (int nf = 0; nf < 4; nf++) b0[nf] = *(const short8*)(bp + (ks + 2) * 2048 + nf * 512);
#pragma unroll
        for (int nf = 0; nf < 4; nf++)
            acc[nf] = __builtin_amdgcn_mfma_f32_16x16x32_bf16(a1, b1[nf], acc[nf], 0, 0, 0);
    }

    // ---- fused el/er ----
    float aL[4], aR[4];
#pragma unroll
    for (int nf = 0; nf < 4; nf++) {
        aL[nf] = avec[nf * 16 + l15];
        aR[nf] = avec[Fq + nf * 16 + l15];
    }
    const int bb = row0 >> 11;
    const int bh = bb * Hq + h;
#pragma unroll
    for (int r = 0; r < 4; r++) {
        float pl = acc[0][r] * aL[0] + acc[1][r] * aL[1] + acc[2][r] * aL[2] + acc[3][r] * aL[3];
        float pr = acc[0][r] * aR[0] + acc[1][r] * aR[1] + acc[2][r] * aR[2] + acc[3][r] * aR[3];
#pragma unroll
        for (int off = 1; off < 16; off <<= 1) {
            pl += __shfl_xor(pl, off, 64);
            pr += __shfl_xor(pr, off, 64);
        }
        if (l15 == 0) {
            int n = (row0 + quad * 4 + r) & (Nq - 1);
            el_t[(size_t)bh * Nq + n] = pl;
            er_t[(size_t)bh * Nq + n] = pr;
        }
    }

    // ---- Vfrag: C in attn B-fragment order (validated R3/R4) ----
    const int n_base = row0 & (Nq - 1);
    const int sblk   = n_base >> 5;
    const int quadp  = ((wv & 1) << 1) | (quad >> 1);
    const int jj0    = (quad & 1) * 4;
#pragma unroll
    for (int nf = 0; nf < 4; nf++) {
        unsigned int r0 = bf16_rne(acc[nf][0]), r1 = bf16_rne(acc[nf][1]);
        unsigned int r2 = bf16_rne(acc[nf][2]), r3 = bf16_rne(acc[nf][3]);
        uint2 pk;
        pk.x = r0 | (r1 << 16);
        pk.y = r2 | (r3 << 16);
        size_t off = ((((size_t)bh * 64 + sblk) * 4 + nf) * 64 + quadp * 16 + l15) * 8 + jj0;
        *(uint2*)(Vfrag + off) = pk;
    }
}

// ---------------------------------------------------------------------------
// Kernel E: ermax[bh] = max_n er_t[bh][n]  (R4-validated)
// ---------------------------------------------------------------------------
__global__ __launch_bounds__(256) void ermax_kernel(
    const float* __restrict__ er_t, float* __restrict__ ermax)
{
    const int bh = blockIdx.x;
    const int t  = threadIdx.x;
    float m = -INFINITY;
    for (int n = t; n < Nq; n += 256) m = fmaxf(m, er_t[(size_t)bh * Nq + n]);
#pragma unroll
    for (int off = 32; off > 0; off >>= 1) m = fmaxf(m, __shfl_xor(m, off, 64));
    __shared__ float sm[4];
    if ((t & 63) == 0) sm[t >> 6] = m;
    __syncthreads();
    if (t == 0) ermax[bh] = fmaxf(fmaxf(sm[0], sm[1]), fmaxf(sm[2], sm[3]));
}

// ---------------------------------------------------------------------------
// Kernel F: MFMA attention, 32 rows/block, K-split 4 (one wave per K-quarter).
// De-spilled vs R4: NO __launch_bounds__ cap, NO manual ping-pong macros —
// plain loop; compiler schedules loads across MFMAs. __expf (R4-validated math).
// ---------------------------------------------------------------------------
__global__ __launch_bounds__(256) void attn_kernel(
    const float* __restrict__ el_t, const float* __restrict__ er_t,
    const float* __restrict__ ermax, const ushort* __restrict__ Vfrag,
    const unsigned int* __restrict__ ebT, float* __restrict__ attn)
{
    const int lane = threadIdx.x & 63;
    const int kh   = threadIdx.x >> 6;     // K-split index 0..3
    const int quad = lane >> 4;
    const int l15  = lane & 15;
    const int bid  = blockIdx.x;           // B*H*64 = 1024
    const int it   = bid & 63;
    const int h    = (bid >> 6) & 7;
    const int b    = bid >> 9;
    const int bh   = b * Hq + h;
    const int i0   = it * 32;

    const float emax = ermax[bh];
    const float elv0 = el_t[(size_t)bh * Nq + i0 + l15];
    const float elv1 = el_t[(size_t)bh * Nq + i0 + 16 + l15];
    const float xm0 = elv0 + emax, xm1 = elv1 + emax;
    const float m0 = fmaxf(xm0, NEG * xm0);    // safe shift: s - m <= 0
    const float m1 = fmaxf(xm1, NEG * xm1);
    const float c10 = elv0 - m0, c20 = NEG * elv0 - m0;
    const float c11 = elv1 - m1, c21 = NEG * elv1 - m1;

    const float*        erp = er_t + (size_t)bh * Nq + kh * 512;          // + s*32
    const ushort*       vp  = Vfrag + (size_t)bh * 131072 + kh * 32768 + lane * 8; // + s*2048
    const unsigned int* e0p = ebT + ((size_t)b * 64 + kh * 16) * Nq + i0 + l15;    // + s*2048

    f32x4 zero4 = {0.f, 0.f, 0.f, 0.f};
    f32x4 acc0[4] = {zero4, zero4, zero4, zero4};
    f32x4 acc1[4] = {zero4, zero4, zero4, zero4};
    float l0 = 0.f, l1 = 0.f;

    for (int s = 0; s < 16; s++) {
        short8 vb0 = *(const short8*)(vp + s * 2048);
        short8 vb1 = *(const short8*)(vp + s * 2048 + 512);
        short8 vb2 = *(const short8*)(vp + s * 2048 + 1024);
        short8 vb3 = *(const short8*)(vp + s * 2048 + 1536);
        unsigned int w0 = e0p[(size_t)s * Nq];
        unsigned int w1 = e0p[(size_t)s * Nq + 16];
        float4 ea  = *(const float4*)(erp + s * 32 + quad * 8);
        float4 ebv = *(const float4*)(erp + s * 32 + quad * 8 + 4);

        const unsigned int wq0 = w0 >> (quad * 8);
        const unsigned int wq1 = w1 >> (quad * 8);
        float er8[8] = {ea.x, ea.y, ea.z, ea.w, ebv.x, ebv.y, ebv.z, ebv.w};
        unsigned int u0[8], u1[8];
#pragma unroll
        for (int jj = 0; jj < 8; jj++) {
            float e  = er8[jj];
            float t0 = fmaxf(e + c10, fmaf(NEG, e, c20));
            float t1 = fmaxf(e + c11, fmaf(NEG, e, c21));
            float x0 = __expf(t0);
            float x1 = __expf(t1);
            int k0 = ((int)(wq0 << (31 - jj))) >> 31;
            int k1 = ((int)(wq1 << (31 - jj))) >> 31;
            u0[jj] = __float_as_uint(x0) & (unsigned int)k0;
            u1[jj] = __float_as_uint(x1) & (unsigned int)k1;
            l0 += __uint_as_float(u0[jj]);
            l1 += __uint_as_float(u1[jj]);
        }
        union { short8 s8; unsigned int w[4]; } af0, af1;
        af0.w[0] = __builtin_amdgcn_perm(u0[1], u0[0], 0x07060302);
        af0.w[1] = __builtin_amdgcn_perm(u0[3], u0[2], 0x07060302);
        af0.w[2] = __builtin_amdgcn_perm(u0[5], u0[4], 0x07060302);
        af0.w[3] = __builtin_amdgcn_perm(u0[7], u0[6], 0x07060302);
        af1.w[0] = __builtin_amdgcn_perm(u1[1], u1[0], 0x07060302);
        af1.w[1] = __builtin_amdgcn_perm(u1[3], u1[2], 0x07060302);
        af1.w[2] = __builtin_amdgcn_perm(u1[5], u1[4], 0x07060302);
        af1.w[3] = __builtin_amdgcn_perm(u1[7], u1[6], 0x07060302);

        acc0[0] = __builtin_amdgcn_mfma_f32_16x16x32_bf16(af0.s8, vb0, acc0[0], 0, 0, 0);
        acc1[0] = __builtin_amdgcn_mfma_f32_16x16x32_bf16(af1.s8, vb0, acc1[0], 0, 0, 0);
        acc0[1] = __builtin_amdgcn_mfma_f32_16x16x32_bf16(af0.s8, vb1, acc0[1], 0, 0, 0);
        acc1[1] = __builtin_amdgcn_mfma_f32_16x16x32_bf16(af1.s8, vb1, acc1[1], 0, 0, 0);
        acc0[2] = __builtin_amdgcn_mfma_f32_16x16x32_bf16(af0.s8, vb2, acc0[2], 0, 0, 0);
        acc1[2] = __builtin_amdgcn_mfma_f32_16x16x32_bf16(af1.s8, vb2, acc1[2], 0, 0, 0);
        acc0[3] = __builtin_amdgcn_mfma_f32_16x16x32_bf16(af0.s8, vb3, acc0[3], 0, 0, 0);
        acc1[3] = __builtin_amdgcn_mfma_f32_16x16x32_bf16(af1.s8, vb3, acc1[3], 0, 0, 0);
    }

    // ---- combine 4 K-splits via LDS (validated R4) ----
    __shared__ float lds_acc[3][32][64];
    __shared__ float lds_l[3][2][64];
    if (kh > 0) {
#pragma unroll
        for (int nf = 0; nf < 4; nf++)
#pragma unroll
            for (int r = 0; r < 4; r++) {
                lds_acc[kh - 1][nf * 4 + r][lane]      = acc0[nf][r];
                lds_acc[kh - 1][16 + nf * 4 + r][lane] = acc1[nf][r];
            }
        lds_l[kh - 1][0][lane] = l0;
        lds_l[kh - 1][1][lane] = l1;
    }
    __syncthreads();
    if (kh == 0) {
#pragma unroll
        for (int q = 0; q < 3; q++) {
#pragma unroll
            for (int nf = 0; nf < 4; nf++)
#pragma unroll
                for (int r = 0; r < 4; r++) {
                    acc0[nf][r] += lds_acc[q][nf * 4 + r][lane];
                    acc1[nf][r] += lds_acc[q][16 + nf * 4 + r][lane];
                }
            l0 += lds_l[q][0][lane];
            l1 += lds_l[q][1][lane];
        }
        l0 += __shfl_xor(l0, 16, 64);
        l0 += __shfl_xor(l0, 32, 64);
        l1 += __shfl_xor(l1, 16, 64);
        l1 += __shfl_xor(l1, 32, 64);
        float lr0[4], lr1[4];
#pragma unroll
        for (int r = 0; r < 4; r++) {
            lr0[r] = __shfl(l0, quad * 4 + r, 64);
            lr1[r] = __shfl(l1, quad * 4 + r, 64);
        }
#pragma unroll
        for (int nf = 0; nf < 4; nf++)
#pragma unroll
            for (int r = 0; r < 4; r++) {
                attn[(((size_t)b * Nq + i0 + quad * 4 + r) * Hq + h) * Fq + nf * 16 + l15] =
                    acc0[nf][r] / lr0[r];
                attn[(((size_t)b * Nq + i0 + 16 + quad * 4 + r) * Hq + h) * Fq + nf * 16 + l15] =
                    acc1[nf][r] / lr1[r];
            }
    }
}

// ---------------------------------------------------------------------------
// Kernel G: out[b,i,f] = sigmoid( mean_h attn[b,i,h,f] )
// ---------------------------------------------------------------------------
__global__ __launch_bounds__(256) void out_kernel(
    const float* __restrict__ attn, float* __restrict__ out)
{
    const int idx = blockIdx.x * 256 + threadIdx.x;
    const int f   = idx & 63;
    const int bn  = idx >> 6;
    const float* p = attn + (size_t)bn * Hq * Fq + f;
    float s = 0.f;
#pragma unroll
    for (int h = 0; h < Hq; h++) s += p[h * Fq];
    s *= (1.f / Hq);
    out[idx] = 1.f / (1.f + __expf(-s));
}

// ---------------------------------------------------------------------------
extern "C" void kernel_launch(void* const* d_in, const int* in_sizes, int n_in,
                              void* d_out, int out_size, void* d_ws, size_t ws_size,
                              hipStream_t stream) {
    const float* nodes = (const float*)d_in[0];   // (2,2048,512)
    const int*   edges = (const int*)d_in[1];     // (2,2048,2048,1)
    const float* W     = (const float*)d_in[2];   // (512,512)
    const float* a     = (const float*)d_in[3];   // (128,)
    float* out = (float*)d_out;                   // (2,2048,64)

    char* ws = (char*)d_ws;
    ushort* Afrag = (ushort*)ws;           ws += (size_t)Bq * Nq * DIN * 2;           // 4 MB
    ushort* Wfrag = (ushort*)ws;           ws += (size_t)DIN * Hq * Fq * 2;           // 512 KB
    ushort* Vfrag = (ushort*)ws;           ws += (size_t)Bq * Hq * Nq * Fq * 2;       // 4 MB
    float*  el_t  = (float*)ws;            ws += (size_t)Bq * Hq * Nq * 4;            // 128 KB
    float*  er_t  = (float*)ws;            ws += (size_t)Bq * Hq * Nq * 4;            // 128 KB
    unsigned int* ebT = (unsigned int*)ws; ws += (size_t)Bq * (Nq / 32) * Nq * 4;     // 1 MB
    float*  ermax = (float*)ws;            ws += 1024;
    float*  attn  = (float*)ws;                                                       // 16 MB

    afrag_kernel<<<(Bq * Nq) / 16, 256, 0, stream>>>(nodes, Afrag);
    wfrag_kernel<<<dim3(DIN / 32, Hq), 256, 0, stream>>>(W, Wfrag);
    pack_edges_kernel<<<((size_t)Bq * Nq * Nq) / 256, 256, 0, stream>>>(edges, ebT);
    gemm_kernel<<<dim3((Bq * Nq) / 64, Hq), 256, 0, stream>>>(Afrag, Wfrag, a, Vfrag, el_t, er_t);
    ermax_kernel<<<Bq * Hq, 256, 0, stream>>>(er_t, ermax);
    attn_kernel<<<Bq * Hq * (Nq / 64), 256, 0, stream>>>(el_t, er_t, ermax, Vfrag, ebT, attn);
    out_kernel<<<(Bq * Nq * Fq) / 256, 256, 0, stream>>>(attn, out);
}

// Round 8
// 121.777 us; speedup vs baseline: 8.2791x; 1.0543x over previous
//
#include <hip/hip_runtime.h>
#include <hip/hip_bf16.h>
#include <math.h>

// Problem constants (B, N, D_IN, H, F) = (2, 2048, 512, 8, 64)
#define Bq   2
#define Nq   2048
#define DIN  512
#define Hq   8
#define Fq   64
#define NEG  0.2f

using short8 = __attribute__((ext_vector_type(8))) short;   // 8 bf16 (4 VGPRs)
using f32x4  = __attribute__((ext_vector_type(4))) float;   // MFMA C/D

__device__ inline unsigned int bf16_rne(float x) {
    unsigned int u = __float_as_uint(x);
    u += 0x7fffu + ((u >> 16) & 1u);
    return u >> 16;
}

// ---------------------------------------------------------------------------
// Kernel 1 (prep): afrag (256 blocks) + wfrag (128 blocks), R7-validated bodies.
//   Afrag[(mt*16+ks)*64 + lane] octet jj = A[mt*16+(lane&15)][ks*32+(lane>>4)*8+jj]
//   Wfrag[((h*16+ks)*4+nf)*64+lane] jj   = W[ks*32+(lane>>4)*8+jj][h*64+nf*16+(lane&15)]
// ---------------------------------------------------------------------------
#define AFRAG_BLOCKS 256
#define WFRAG_BLOCKS 128

__global__ __launch_bounds__(256) void prep_kernel(
    const float* __restrict__ nodes, ushort* __restrict__ Afrag,
    const float* __restrict__ W,     ushort* __restrict__ Wfrag)
{
    __shared__ __align__(16) char smem[16 * 516 * 4];   // 33 KB: max(As, Ws)
    const int bid = blockIdx.x;
    const int t   = threadIdx.x;

    if (bid < AFRAG_BLOCKS) {
        float (*As)[516] = (float(*)[516])smem;
        const int mt = bid;
        {
            const int row = t >> 4, c = t & 15;
#pragma unroll
            for (int i = 0; i < 8; i++) {
                float4 v = *(const float4*)&nodes[((size_t)mt * 16 + row) * DIN + (c + i * 16) * 4];
                *(float4*)&As[row][(c + i * 16) * 4] = v;
            }
        }
        __syncthreads();
        const int lane = t & 63, ksg = t >> 6;
        const int quad = lane >> 4, l15 = lane & 15;
#pragma unroll
        for (int k2 = 0; k2 < 4; k2++) {
            int ks = ksg * 4 + k2;
            const float* src = &As[l15][ks * 32 + quad * 8];
            float4 f0 = *(const float4*)src;
            float4 f1 = *(const float4*)(src + 4);
            uint4 pk;
            pk.x = bf16_rne(f0.x) | (bf16_rne(f0.y) << 16);
            pk.y = bf16_rne(f0.z) | (bf16_rne(f0.w) << 16);
            pk.z = bf16_rne(f1.x) | (bf16_rne(f1.y) << 16);
            pk.w = bf16_rne(f1.z) | (bf16_rne(f1.w) << 16);
            *(uint4*)(Afrag + ((size_t)(mt * 16 + ks) * 64 + lane) * 8) = pk;
        }
        return;
    }

    {
        float (*Ws)[68] = (float(*)[68])smem;
        const int id = bid - AFRAG_BLOCKS;
        const int ks = id & 15, h = id >> 4;
        {
            const int row = t >> 3, c = t & 7;
            const float* src = &W[(size_t)(ks * 32 + row) * (Hq * Fq) + h * 64 + c * 8];
            float4 v0 = *(const float4*)src;
            float4 v1 = *(const float4*)(src + 4);
            *(float4*)&Ws[row][c * 8]     = v0;
            *(float4*)&Ws[row][c * 8 + 4] = v1;
        }
        __syncthreads();
        const int lane = t & 63, nf = t >> 6;
        const int quad = lane >> 4, l15 = lane & 15;
        float f[8];
#pragma unroll
        for (int jj = 0; jj < 8; jj++) f[jj] = Ws[quad * 8 + jj][nf * 16 + l15];
        uint4 pk;
        pk.x = bf16_rne(f[0]) | (bf16_rne(f[1]) << 16);
        pk.y = bf16_rne(f[2]) | (bf16_rne(f[3]) << 16);
        pk.z = bf16_rne(f[4]) | (bf16_rne(f[5]) << 16);
        pk.w = bf16_rne(f[6]) | (bf16_rne(f[7]) << 16);
        *(uint4*)(Wfrag + (((size_t)(h * 16 + ks) * 4 + nf) * 64 + lane) * 8) = pk;
    }
}

// ---------------------------------------------------------------------------
// Kernel 2 (work): gemm (blocks [0,512), R7-validated) + pack_edges
// (blocks [512, 512+32768), R7-validated, CORRECT bound: B*N*N/256 = 32768).
// pack is HBM-bound and overlaps gemm's MFMA phase.
// ---------------------------------------------------------------------------
#define GEMM_BLOCKS 512
#define PACK_BLOCKS 32768   // B*N*N / 256 = 2*2048*2048/256

__global__ __launch_bounds__(256) void work_kernel(
    const ushort* __restrict__ Afrag, const ushort* __restrict__ Wfrag,
    const float*  __restrict__ avec,
    ushort* __restrict__ Vfrag,      // [16 bh][64 s][4 nf][64 lane][8] bf16
    float* __restrict__ el_t,        // [16][2048]
    float* __restrict__ er_t,        // [16][2048]
    const int* __restrict__ edges, unsigned int* __restrict__ ebT)
{
    const int bid = blockIdx.x;
    const int t   = threadIdx.x;

    if (bid >= GEMM_BLOCKS) {
        // ---- pack edges -> transposed bitmask ebT[b][jword(64)][i(2048)] ----
        int gid = (bid - GEMM_BLOCKS) * 256 + t;
        unsigned long long m = __ballot(edges[gid] != 0);
        int lane = t & 63;
        int b = gid >> 22;
        int i = (gid >> 11) & 2047;
        int j = gid & 2047;
        if (lane == 0)
            ebT[((size_t)b * 64 + (j >> 5)) * Nq + i] = (unsigned int)m;
        else if (lane == 32)
            ebT[((size_t)b * 64 + (j >> 5)) * Nq + i] = (unsigned int)(m >> 32);
        return;
    }

    // ---- gemm: R7-validated body ----
    const int lane = t & 63;
    const int wv   = t >> 6;
    const int quad = lane >> 4;
    const int l15  = lane & 15;
    const int h    = bid >> 6;            // 0..7
    const int mt   = (bid & 63) * 4 + wv; // 0..255
    const int row0 = mt * 16;

    const ushort* ap = Afrag + (size_t)mt * 8192 + lane * 8;   // + ks*512
    const ushort* bp = Wfrag + (size_t)h * 32768 + lane * 8;   // + ks*2048 + nf*512

    f32x4 zero4 = {0.f, 0.f, 0.f, 0.f};
    f32x4 acc[4] = {zero4, zero4, zero4, zero4};

    short8 a0, a1, b0[4], b1[4];
    a0 = *(const short8*)(ap);
#pragma unroll
    for (int nf = 0; nf < 4; nf++) b0[nf] = *(const short8*)(bp + nf * 512);

    for (int ks = 0; ks < 16; ks += 2) {
        a1 = *(const short8*)(ap + (ks + 1) * 512);
#pragma unroll
        for (int nf = 0; nf < 4; nf++) b1[nf] = *(const short8*)(bp + (ks + 1) * 2048 + nf * 512);
#pragma unroll
        for (int nf = 0; nf < 4; nf++)
            acc[nf] = __builtin_amdgcn_mfma_f32_16x16x32_bf16(a0, b0[nf], acc[nf], 0, 0, 0);
        a0 = *(const short8*)(ap + (ks + 2) * 512);   // ks=14 -> past end: lands in Wfrag, unused
#pragma unroll
        for (int nf = 0; nf < 4; nf++) b0[nf] = *(const short8*)(bp + (ks + 2) * 2048 + nf * 512);
#pragma unroll
        for (int nf = 0; nf < 4; nf++)
            acc[nf] = __builtin_amdgcn_mfma_f32_16x16x32_bf16(a1, b1[nf], acc[nf], 0, 0, 0);
    }

    // ---- fused el/er ----
    float aL[4], aR[4];
#pragma unroll
    for (int nf = 0; nf < 4; nf++) {
        aL[nf] = avec[nf * 16 + l15];
        aR[nf] = avec[Fq + nf * 16 + l15];
    }
    const int bb = row0 >> 11;
    const int bh = bb * Hq + h;
#pragma unroll
    for (int r = 0; r < 4; r++) {
        float pl = acc[0][r] * aL[0] + acc[1][r] * aL[1] + acc[2][r] * aL[2] + acc[3][r] * aL[3];
        float pr = acc[0][r] * aR[0] + acc[1][r] * aR[1] + acc[2][r] * aR[2] + acc[3][r] * aR[3];
#pragma unroll
        for (int off = 1; off < 16; off <<= 1) {
            pl += __shfl_xor(pl, off, 64);
            pr += __shfl_xor(pr, off, 64);
        }
        if (l15 == 0) {
            int n = (row0 + quad * 4 + r) & (Nq - 1);
            el_t[(size_t)bh * Nq + n] = pl;
            er_t[(size_t)bh * Nq + n] = pr;
        }
    }

    // ---- Vfrag: C in attn B-fragment order (validated R3/R4/R7) ----
    const int n_base = row0 & (Nq - 1);
    const int sblk   = n_base >> 5;
    const int quadp  = ((wv & 1) << 1) | (quad >> 1);
    const int jj0    = (quad & 1) * 4;
#pragma unroll
    for (int nf = 0; nf < 4; nf++) {
        unsigned int r0 = bf16_rne(acc[nf][0]), r1 = bf16_rne(acc[nf][1]);
        unsigned int r2 = bf16_rne(acc[nf][2]), r3 = bf16_rne(acc[nf][3]);
        uint2 pk;
        pk.x = r0 | (r1 << 16);
        pk.y = r2 | (r3 << 16);
        size_t off = ((((size_t)bh * 64 + sblk) * 4 + nf) * 64 + quadp * 16 + l15) * 8 + jj0;
        *(uint2*)(Vfrag + off) = pk;
    }
}

// ---------------------------------------------------------------------------
// Kernel 3: MFMA attention (R7-validated) + INLINE ermax (replaces the
// 16-block ermax kernel: each block reduces er_t[bh][:] = 8 KB itself).
// ---------------------------------------------------------------------------
__global__ __launch_bounds__(256) void attn_kernel(
    const float* __restrict__ el_t, const float* __restrict__ er_t,
    const ushort* __restrict__ Vfrag,
    const unsigned int* __restrict__ ebT, float* __restrict__ attn)
{
    const int lane = threadIdx.x & 63;
    const int kh   = threadIdx.x >> 6;     // K-split index 0..3
    const int quad = lane >> 4;
    const int l15  = lane & 15;
    const int bid  = blockIdx.x;           // B*H*64 = 1024
    const int it   = bid & 63;
    const int h    = (bid >> 6) & 7;
    const int b    = bid >> 9;
    const int bh   = b * Hq + h;
    const int i0   = it * 32;

    // ---- inline ermax over er_t[bh][:] ----
    __shared__ float smax[4];
    const float* errow = er_t + (size_t)bh * Nq;
    float mx = -INFINITY;
#pragma unroll
    for (int ii = 0; ii < 8; ii++) mx = fmaxf(mx, errow[threadIdx.x + ii * 256]);
#pragma unroll
    for (int off = 32; off > 0; off >>= 1) mx = fmaxf(mx, __shfl_xor(mx, off, 64));
    if (lane == 0) smax[kh] = mx;
    __syncthreads();
    const float emax = fmaxf(fmaxf(smax[0], smax[1]), fmaxf(smax[2], smax[3]));

    const float elv0 = el_t[(size_t)bh * Nq + i0 + l15];
    const float elv1 = el_t[(size_t)bh * Nq + i0 + 16 + l15];
    const float xm0 = elv0 + emax, xm1 = elv1 + emax;
    const float m0 = fmaxf(xm0, NEG * xm0);    // safe shift: s - m <= 0
    const float m1 = fmaxf(xm1, NEG * xm1);
    const float c10 = elv0 - m0, c20 = NEG * elv0 - m0;
    const float c11 = elv1 - m1, c21 = NEG * elv1 - m1;

    const float*        erp = er_t + (size_t)bh * Nq + kh * 512;          // + s*32
    const ushort*       vp  = Vfrag + (size_t)bh * 131072 + kh * 32768 + lane * 8; // + s*2048
    const unsigned int* e0p = ebT + ((size_t)b * 64 + kh * 16) * Nq + i0 + l15;    // + s*2048

    f32x4 zero4 = {0.f, 0.f, 0.f, 0.f};
    f32x4 acc0[4] = {zero4, zero4, zero4, zero4};
    f32x4 acc1[4] = {zero4, zero4, zero4, zero4};
    float l0 = 0.f, l1 = 0.f;

    for (int s = 0; s < 16; s++) {
        short8 vb0 = *(const short8*)(vp + s * 2048);
        short8 vb1 = *(const short8*)(vp + s * 2048 + 512);
        short8 vb2 = *(const short8*)(vp + s * 2048 + 1024);
        short8 vb3 = *(const short8*)(vp + s * 2048 + 1536);
        unsigned int w0 = e0p[(size_t)s * Nq];
        unsigned int w1 = e0p[(size_t)s * Nq + 16];
        float4 ea  = *(const float4*)(erp + s * 32 + quad * 8);
        float4 ebv = *(const float4*)(erp + s * 32 + quad * 8 + 4);

        const unsigned int wq0 = w0 >> (quad * 8);
        const unsigned int wq1 = w1 >> (quad * 8);
        float er8[8] = {ea.x, ea.y, ea.z, ea.w, ebv.x, ebv.y, ebv.z, ebv.w};
        unsigned int u0[8], u1[8];
#pragma unroll
        for (int jj = 0; jj < 8; jj++) {
            float e  = er8[jj];
            float t0 = fmaxf(e + c10, fmaf(NEG, e, c20));
            float t1 = fmaxf(e + c11, fmaf(NEG, e, c21));
            float x0 = __expf(t0);
            float x1 = __expf(t1);
            int k0 = ((int)(wq0 << (31 - jj))) >> 31;
            int k1 = ((int)(wq1 << (31 - jj))) >> 31;
            u0[jj] = __float_as_uint(x0) & (unsigned int)k0;
            u1[jj] = __float_as_uint(x1) & (unsigned int)k1;
            l0 += __uint_as_float(u0[jj]);
            l1 += __uint_as_float(u1[jj]);
        }
        union { short8 s8; unsigned int w[4]; } af0, af1;
        af0.w[0] = __builtin_amdgcn_perm(u0[1], u0[0], 0x07060302);
        af0.w[1] = __builtin_amdgcn_perm(u0[3], u0[2], 0x07060302);
        af0.w[2] = __builtin_amdgcn_perm(u0[5], u0[4], 0x07060302);
        af0.w[3] = __builtin_amdgcn_perm(u0[7], u0[6], 0x07060302);
        af1.w[0] = __builtin_amdgcn_perm(u1[1], u1[0], 0x07060302);
        af1.w[1] = __builtin_amdgcn_perm(u1[3], u1[2], 0x07060302);
        af1.w[2] = __builtin_amdgcn_perm(u1[5], u1[4], 0x07060302);
        af1.w[3] = __builtin_amdgcn_perm(u1[7], u1[6], 0x07060302);

        acc0[0] = __builtin_amdgcn_mfma_f32_16x16x32_bf16(af0.s8, vb0, acc0[0], 0, 0, 0);
        acc1[0] = __builtin_amdgcn_mfma_f32_16x16x32_bf16(af1.s8, vb0, acc1[0], 0, 0, 0);
        acc0[1] = __builtin_amdgcn_mfma_f32_16x16x32_bf16(af0.s8, vb1, acc0[1], 0, 0, 0);
        acc1[1] = __builtin_amdgcn_mfma_f32_16x16x32_bf16(af1.s8, vb1, acc1[1], 0, 0, 0);
        acc0[2] = __builtin_amdgcn_mfma_f32_16x16x32_bf16(af0.s8, vb2, acc0[2], 0, 0, 0);
        acc1[2] = __builtin_amdgcn_mfma_f32_16x16x32_bf16(af1.s8, vb2, acc1[2], 0, 0, 0);
        acc0[3] = __builtin_amdgcn_mfma_f32_16x16x32_bf16(af0.s8, vb3, acc0[3], 0, 0, 0);
        acc1[3] = __builtin_amdgcn_mfma_f32_16x16x32_bf16(af1.s8, vb3, acc1[3], 0, 0, 0);
    }

    // ---- combine 4 K-splits via LDS (validated R4/R7) ----
    __shared__ float lds_acc[3][32][64];
    __shared__ float lds_l[3][2][64];
    if (kh > 0) {
#pragma unroll
        for (int nf = 0; nf < 4; nf++)
#pragma unroll
            for (int r = 0; r < 4; r++) {
                lds_acc[kh - 1][nf * 4 + r][lane]      = acc0[nf][r];
                lds_acc[kh - 1][16 + nf * 4 + r][lane] = acc1[nf][r];
            }
        lds_l[kh - 1][0][lane] = l0;
        lds_l[kh - 1][1][lane] = l1;
    }
    __syncthreads();
    if (kh == 0) {
#pragma unroll
        for (int q = 0; q < 3; q++) {
#pragma unroll
            for (int nf = 0; nf < 4; nf++)
#pragma unroll
                for (int r = 0; r < 4; r++) {
                    acc0[nf][r] += lds_acc[q][nf * 4 + r][lane];
                    acc1[nf][r] += lds_acc[q][16 + nf * 4 + r][lane];
                }
            l0 += lds_l[q][0][lane];
            l1 += lds_l[q][1][lane];
        }
        l0 += __shfl_xor(l0, 16, 64);
        l0 += __shfl_xor(l0, 32, 64);
        l1 += __shfl_xor(l1, 16, 64);
        l1 += __shfl_xor(l1, 32, 64);
        float lr0[4], lr1[4];
#pragma unroll
        for (int r = 0; r < 4; r++) {
            lr0[r] = __shfl(l0, quad * 4 + r, 64);
            lr1[r] = __shfl(l1, quad * 4 + r, 64);
        }
#pragma unroll
        for (int nf = 0; nf < 4; nf++)
#pragma unroll
            for (int r = 0; r < 4; r++) {
                attn[(((size_t)b * Nq + i0 + quad * 4 + r) * Hq + h) * Fq + nf * 16 + l15] =
                    acc0[nf][r] / lr0[r];
                attn[(((size_t)b * Nq + i0 + 16 + quad * 4 + r) * Hq + h) * Fq + nf * 16 + l15] =
                    acc1[nf][r] / lr1[r];
            }
    }
}

// ---------------------------------------------------------------------------
// Kernel 4: out[b,i,f] = sigmoid( mean_h attn[b,i,h,f] )
// ---------------------------------------------------------------------------
__global__ __launch_bounds__(256) void out_kernel(
    const float* __restrict__ attn, float* __restrict__ out)
{
    const int idx = blockIdx.x * 256 + threadIdx.x;
    const int f   = idx & 63;
    const int bn  = idx >> 6;
    const float* p = attn + (size_t)bn * Hq * Fq + f;
    float s = 0.f;
#pragma unroll
    for (int h = 0; h < Hq; h++) s += p[h * Fq];
    s *= (1.f / Hq);
    out[idx] = 1.f / (1.f + __expf(-s));
}

// ---------------------------------------------------------------------------
extern "C" void kernel_launch(void* const* d_in, const int* in_sizes, int n_in,
                              void* d_out, int out_size, void* d_ws, size_t ws_size,
                              hipStream_t stream) {
    const float* nodes = (const float*)d_in[0];   // (2,2048,512)
    const int*   edges = (const int*)d_in[1];     // (2,2048,2048,1)
    const float* W     = (const float*)d_in[2];   // (512,512)
    const float* a     = (const float*)d_in[3];   // (128,)
    float* out = (float*)d_out;                   // (2,2048,64)

    char* ws = (char*)d_ws;
    ushort* Afrag = (ushort*)ws;           ws += (size_t)Bq * Nq * DIN * 2;           // 4 MB
    ushort* Wfrag = (ushort*)ws;           ws += (size_t)DIN * Hq * Fq * 2;           // 512 KB
    ushort* Vfrag = (ushort*)ws;           ws += (size_t)Bq * Hq * Nq * Fq * 2;       // 4 MB
    float*  el_t  = (float*)ws;            ws += (size_t)Bq * Hq * Nq * 4;            // 128 KB
    float*  er_t  = (float*)ws;            ws += (size_t)Bq * Hq * Nq * 4;            // 128 KB
    unsigned int* ebT = (unsigned int*)ws; ws += (size_t)Bq * (Nq / 32) * Nq * 4;     // 1 MB
    float*  attn  = (float*)ws;                                                       // 16 MB

    prep_kernel<<<AFRAG_BLOCKS + WFRAG_BLOCKS, 256, 0, stream>>>(nodes, Afrag, W, Wfrag);
    work_kernel<<<GEMM_BLOCKS + PACK_BLOCKS, 256, 0, stream>>>(
        Afrag, Wfrag, a, Vfrag, el_t, er_t, edges, ebT);
    attn_kernel<<<Bq * Hq * (Nq / 64), 256, 0, stream>>>(el_t, er_t, Vfrag, ebT, attn);
    out_kernel<<<(Bq * Nq * Fq) / 256, 256, 0, stream>>>(attn, out);
}

// Round 9
// 115.773 us; speedup vs baseline: 8.7085x; 1.0519x over previous
//
#include <hip/hip_runtime.h>
#include <hip/hip_bf16.h>
#include <math.h>

// Problem constants (B, N, D_IN, H, F) = (2, 2048, 512, 8, 64)
#define Bq   2
#define Nq   2048
#define DIN  512
#define Hq   8
#define Fq   64
#define NEG  0.2f

using short8 = __attribute__((ext_vector_type(8))) short;   // 8 bf16 (4 VGPRs)
using f32x4  = __attribute__((ext_vector_type(4))) float;   // MFMA C/D

__device__ inline unsigned int bf16_rne(float x) {
    unsigned int u = __float_as_uint(x);
    u += 0x7fffu + ((u >> 16) & 1u);
    return u >> 16;
}

// ---------------------------------------------------------------------------
// Kernel 1 (prep): afrag (256 blocks) + wfrag (128 blocks), R8-validated.
// ---------------------------------------------------------------------------
#define AFRAG_BLOCKS 256
#define WFRAG_BLOCKS 128

__global__ __launch_bounds__(256) void prep_kernel(
    const float* __restrict__ nodes, ushort* __restrict__ Afrag,
    const float* __restrict__ W,     ushort* __restrict__ Wfrag)
{
    __shared__ __align__(16) char smem[16 * 516 * 4];   // 33 KB: max(As, Ws)
    const int bid = blockIdx.x;
    const int t   = threadIdx.x;

    if (bid < AFRAG_BLOCKS) {
        float (*As)[516] = (float(*)[516])smem;
        const int mt = bid;
        {
            const int row = t >> 4, c = t & 15;
#pragma unroll
            for (int i = 0; i < 8; i++) {
                float4 v = *(const float4*)&nodes[((size_t)mt * 16 + row) * DIN + (c + i * 16) * 4];
                *(float4*)&As[row][(c + i * 16) * 4] = v;
            }
        }
        __syncthreads();
        const int lane = t & 63, ksg = t >> 6;
        const int quad = lane >> 4, l15 = lane & 15;
#pragma unroll
        for (int k2 = 0; k2 < 4; k2++) {
            int ks = ksg * 4 + k2;
            const float* src = &As[l15][ks * 32 + quad * 8];
            float4 f0 = *(const float4*)src;
            float4 f1 = *(const float4*)(src + 4);
            uint4 pk;
            pk.x = bf16_rne(f0.x) | (bf16_rne(f0.y) << 16);
            pk.y = bf16_rne(f0.z) | (bf16_rne(f0.w) << 16);
            pk.z = bf16_rne(f1.x) | (bf16_rne(f1.y) << 16);
            pk.w = bf16_rne(f1.z) | (bf16_rne(f1.w) << 16);
            *(uint4*)(Afrag + ((size_t)(mt * 16 + ks) * 64 + lane) * 8) = pk;
        }
        return;
    }

    {
        float (*Ws)[68] = (float(*)[68])smem;
        const int id = bid - AFRAG_BLOCKS;
        const int ks = id & 15, h = id >> 4;
        {
            const int row = t >> 3, c = t & 7;
            const float* src = &W[(size_t)(ks * 32 + row) * (Hq * Fq) + h * 64 + c * 8];
            float4 v0 = *(const float4*)src;
            float4 v1 = *(const float4*)(src + 4);
            *(float4*)&Ws[row][c * 8]     = v0;
            *(float4*)&Ws[row][c * 8 + 4] = v1;
        }
        __syncthreads();
        const int lane = t & 63, nf = t >> 6;
        const int quad = lane >> 4, l15 = lane & 15;
        float f[8];
#pragma unroll
        for (int jj = 0; jj < 8; jj++) f[jj] = Ws[quad * 8 + jj][nf * 16 + l15];
        uint4 pk;
        pk.x = bf16_rne(f[0]) | (bf16_rne(f[1]) << 16);
        pk.y = bf16_rne(f[2]) | (bf16_rne(f[3]) << 16);
        pk.z = bf16_rne(f[4]) | (bf16_rne(f[5]) << 16);
        pk.w = bf16_rne(f[6]) | (bf16_rne(f[7]) << 16);
        *(uint4*)(Wfrag + (((size_t)(h * 16 + ks) * 4 + nf) * 64 + lane) * 8) = pk;
    }
}

// ---------------------------------------------------------------------------
// Kernel 2 (work): gemm (blocks [0,512), R8-validated) + pack_edges REWRITTEN:
// one thread builds ONE 32-bit mask word via 8 independent int4 loads
// (128 B/thread -> high MLP; old version was 4 B/thread = latency-bound
// ~0.6 TB/s ~ 50 us). gid -> (b, w, i) with i fastest => coalesced writes.
// Bit t of ebT[b][w][i] = edges[b][i][w*32+t] (identical semantics).
// ---------------------------------------------------------------------------
#define GEMM_BLOCKS 512
#define PACK_BLOCKS 1024   // B * 64 words * 2048 rows / 256 threads

__global__ __launch_bounds__(256) void work_kernel(
    const ushort* __restrict__ Afrag, const ushort* __restrict__ Wfrag,
    const float*  __restrict__ avec,
    ushort* __restrict__ Vfrag,      // [16 bh][64 s][4 nf][64 lane][8] bf16
    float* __restrict__ el_t,        // [16][2048]
    float* __restrict__ er_t,        // [16][2048]
    const int* __restrict__ edges, unsigned int* __restrict__ ebT)
{
    const int bid = blockIdx.x;
    const int t   = threadIdx.x;

    if (bid >= GEMM_BLOCKS) {
        // ---- pack edges -> transposed bitmask ebT[b][jword(64)][i(2048)] ----
        int gid = (bid - GEMM_BLOCKS) * 256 + t;   // 0..262143
        int i = gid & 2047;
        int w = (gid >> 11) & 63;
        int b = gid >> 17;
        const int4* ep = (const int4*)(edges + (((size_t)b * Nq + i) * Nq + w * 32));
        unsigned int word = 0;
#pragma unroll
        for (int c = 0; c < 8; c++) {
            int4 v = ep[c];
            word |= (v.x != 0 ? 1u : 0u) << (c * 4);
            word |= (v.y != 0 ? 1u : 0u) << (c * 4 + 1);
            word |= (v.z != 0 ? 1u : 0u) << (c * 4 + 2);
            word |= (v.w != 0 ? 1u : 0u) << (c * 4 + 3);
        }
        ebT[((size_t)b * 64 + w) * Nq + i] = word;
        return;
    }

    // ---- gemm: R8-validated body ----
    const int lane = t & 63;
    const int wv   = t >> 6;
    const int quad = lane >> 4;
    const int l15  = lane & 15;
    const int h    = bid >> 6;            // 0..7
    const int mt   = (bid & 63) * 4 + wv; // 0..255
    const int row0 = mt * 16;

    const ushort* ap = Afrag + (size_t)mt * 8192 + lane * 8;   // + ks*512
    const ushort* bp = Wfrag + (size_t)h * 32768 + lane * 8;   // + ks*2048 + nf*512

    f32x4 zero4 = {0.f, 0.f, 0.f, 0.f};
    f32x4 acc[4] = {zero4, zero4, zero4, zero4};

    short8 a0, a1, b0[4], b1[4];
    a0 = *(const short8*)(ap);
#pragma unroll
    for (int nf = 0; nf < 4; nf++) b0[nf] = *(const short8*)(bp + nf * 512);

    for (int ks = 0; ks < 16; ks += 2) {
        a1 = *(const short8*)(ap + (ks + 1) * 512);
#pragma unroll
        for (int nf = 0; nf < 4; nf++) b1[nf] = *(const short8*)(bp + (ks + 1) * 2048 + nf * 512);
#pragma unroll
        for (int nf = 0; nf < 4; nf++)
            acc[nf] = __builtin_amdgcn_mfma_f32_16x16x32_bf16(a0, b0[nf], acc[nf], 0, 0, 0);
        a0 = *(const short8*)(ap + (ks + 2) * 512);   // ks=14 -> past end: lands in Wfrag, unused
#pragma unroll
        for (int nf = 0; nf < 4; nf++) b0[nf] = *(const short8*)(bp + (ks + 2) * 2048 + nf * 512);
#pragma unroll
        for (int nf = 0; nf < 4; nf++)
            acc[nf] = __builtin_amdgcn_mfma_f32_16x16x32_bf16(a1, b1[nf], acc[nf], 0, 0, 0);
    }

    // ---- fused el/er ----
    float aL[4], aR[4];
#pragma unroll
    for (int nf = 0; nf < 4; nf++) {
        aL[nf] = avec[nf * 16 + l15];
        aR[nf] = avec[Fq + nf * 16 + l15];
    }
    const int bb = row0 >> 11;
    const int bh = bb * Hq + h;
#pragma unroll
    for (int r = 0; r < 4; r++) {
        float pl = acc[0][r] * aL[0] + acc[1][r] * aL[1] + acc[2][r] * aL[2] + acc[3][r] * aL[3];
        float pr = acc[0][r] * aR[0] + acc[1][r] * aR[1] + acc[2][r] * aR[2] + acc[3][r] * aR[3];
#pragma unroll
        for (int off = 1; off < 16; off <<= 1) {
            pl += __shfl_xor(pl, off, 64);
            pr += __shfl_xor(pr, off, 64);
        }
        if (l15 == 0) {
            int n = (row0 + quad * 4 + r) & (Nq - 1);
            el_t[(size_t)bh * Nq + n] = pl;
            er_t[(size_t)bh * Nq + n] = pr;
        }
    }

    // ---- Vfrag: C in attn B-fragment order (validated R3/R4/R7/R8) ----
    const int n_base = row0 & (Nq - 1);
    const int sblk   = n_base >> 5;
    const int quadp  = ((wv & 1) << 1) | (quad >> 1);
    const int jj0    = (quad & 1) * 4;
#pragma unroll
    for (int nf = 0; nf < 4; nf++) {
        unsigned int r0 = bf16_rne(acc[nf][0]), r1 = bf16_rne(acc[nf][1]);
        unsigned int r2 = bf16_rne(acc[nf][2]), r3 = bf16_rne(acc[nf][3]);
        uint2 pk;
        pk.x = r0 | (r1 << 16);
        pk.y = r2 | (r3 << 16);
        size_t off = ((((size_t)bh * 64 + sblk) * 4 + nf) * 64 + quadp * 16 + l15) * 8 + jj0;
        *(uint2*)(Vfrag + off) = pk;
    }
}

// ---------------------------------------------------------------------------
// Kernel 3: MFMA attention (R8-validated) + inline ermax.
// ---------------------------------------------------------------------------
__global__ __launch_bounds__(256) void attn_kernel(
    const float* __restrict__ el_t, const float* __restrict__ er_t,
    const ushort* __restrict__ Vfrag,
    const unsigned int* __restrict__ ebT, float* __restrict__ attn)
{
    const int lane = threadIdx.x & 63;
    const int kh   = threadIdx.x >> 6;     // K-split index 0..3
    const int quad = lane >> 4;
    const int l15  = lane & 15;
    const int bid  = blockIdx.x;           // B*H*64 = 1024
    const int it   = bid & 63;
    const int h    = (bid >> 6) & 7;
    const int b    = bid >> 9;
    const int bh   = b * Hq + h;
    const int i0   = it * 32;

    // ---- inline ermax over er_t[bh][:] ----
    __shared__ float smax[4];
    const float* errow = er_t + (size_t)bh * Nq;
    float mx = -INFINITY;
#pragma unroll
    for (int ii = 0; ii < 8; ii++) mx = fmaxf(mx, errow[threadIdx.x + ii * 256]);
#pragma unroll
    for (int off = 32; off > 0; off >>= 1) mx = fmaxf(mx, __shfl_xor(mx, off, 64));
    if (lane == 0) smax[kh] = mx;
    __syncthreads();
    const float emax = fmaxf(fmaxf(smax[0], smax[1]), fmaxf(smax[2], smax[3]));

    const float elv0 = el_t[(size_t)bh * Nq + i0 + l15];
    const float elv1 = el_t[(size_t)bh * Nq + i0 + 16 + l15];
    const float xm0 = elv0 + emax, xm1 = elv1 + emax;
    const float m0 = fmaxf(xm0, NEG * xm0);    // safe shift: s - m <= 0
    const float m1 = fmaxf(xm1, NEG * xm1);
    const float c10 = elv0 - m0, c20 = NEG * elv0 - m0;
    const float c11 = elv1 - m1, c21 = NEG * elv1 - m1;

    const float*        erp = er_t + (size_t)bh * Nq + kh * 512;          // + s*32
    const ushort*       vp  = Vfrag + (size_t)bh * 131072 + kh * 32768 + lane * 8; // + s*2048
    const unsigned int* e0p = ebT + ((size_t)b * 64 + kh * 16) * Nq + i0 + l15;    // + s*2048

    f32x4 zero4 = {0.f, 0.f, 0.f, 0.f};
    f32x4 acc0[4] = {zero4, zero4, zero4, zero4};
    f32x4 acc1[4] = {zero4, zero4, zero4, zero4};
    float l0 = 0.f, l1 = 0.f;

    for (int s = 0; s < 16; s++) {
        short8 vb0 = *(const short8*)(vp + s * 2048);
        short8 vb1 = *(const short8*)(vp + s * 2048 + 512);
        short8 vb2 = *(const short8*)(vp + s * 2048 + 1024);
        short8 vb3 = *(const short8*)(vp + s * 2048 + 1536);
        unsigned int w0 = e0p[(size_t)s * Nq];
        unsigned int w1 = e0p[(size_t)s * Nq + 16];
        float4 ea  = *(const float4*)(erp + s * 32 + quad * 8);
        float4 ebv = *(const float4*)(erp + s * 32 + quad * 8 + 4);

        const unsigned int wq0 = w0 >> (quad * 8);
        const unsigned int wq1 = w1 >> (quad * 8);
        float er8[8] = {ea.x, ea.y, ea.z, ea.w, ebv.x, ebv.y, ebv.z, ebv.w};
        unsigned int u0[8], u1[8];
#pragma unroll
        for (int jj = 0; jj < 8; jj++) {
            float e  = er8[jj];
            float t0 = fmaxf(e + c10, fmaf(NEG, e, c20));
            float t1 = fmaxf(e + c11, fmaf(NEG, e, c21));
            float x0 = __expf(t0);
            float x1 = __expf(t1);
            int k0 = ((int)(wq0 << (31 - jj))) >> 31;
            int k1 = ((int)(wq1 << (31 - jj))) >> 31;
            u0[jj] = __float_as_uint(x0) & (unsigned int)k0;
            u1[jj] = __float_as_uint(x1) & (unsigned int)k1;
            l0 += __uint_as_float(u0[jj]);
            l1 += __uint_as_float(u1[jj]);
        }
        union { short8 s8; unsigned int w[4]; } af0, af1;
        af0.w[0] = __builtin_amdgcn_perm(u0[1], u0[0], 0x07060302);
        af0.w[1] = __builtin_amdgcn_perm(u0[3], u0[2], 0x07060302);
        af0.w[2] = __builtin_amdgcn_perm(u0[5], u0[4], 0x07060302);
        af0.w[3] = __builtin_amdgcn_perm(u0[7], u0[6], 0x07060302);
        af1.w[0] = __builtin_amdgcn_perm(u1[1], u1[0], 0x07060302);
        af1.w[1] = __builtin_amdgcn_perm(u1[3], u1[2], 0x07060302);
        af1.w[2] = __builtin_amdgcn_perm(u1[5], u1[4], 0x07060302);
        af1.w[3] = __builtin_amdgcn_perm(u1[7], u1[6], 0x07060302);

        acc0[0] = __builtin_amdgcn_mfma_f32_16x16x32_bf16(af0.s8, vb0, acc0[0], 0, 0, 0);
        acc1[0] = __builtin_amdgcn_mfma_f32_16x16x32_bf16(af1.s8, vb0, acc1[0], 0, 0, 0);
        acc0[1] = __builtin_amdgcn_mfma_f32_16x16x32_bf16(af0.s8, vb1, acc0[1], 0, 0, 0);
        acc1[1] = __builtin_amdgcn_mfma_f32_16x16x32_bf16(af1.s8, vb1, acc1[1], 0, 0, 0);
        acc0[2] = __builtin_amdgcn_mfma_f32_16x16x32_bf16(af0.s8, vb2, acc0[2], 0, 0, 0);
        acc1[2] = __builtin_amdgcn_mfma_f32_16x16x32_bf16(af1.s8, vb2, acc1[2], 0, 0, 0);
        acc0[3] = __builtin_amdgcn_mfma_f32_16x16x32_bf16(af0.s8, vb3, acc0[3], 0, 0, 0);
        acc1[3] = __builtin_amdgcn_mfma_f32_16x16x32_bf16(af1.s8, vb3, acc1[3], 0, 0, 0);
    }

    // ---- combine 4 K-splits via LDS (validated R4/R7/R8) ----
    __shared__ float lds_acc[3][32][64];
    __shared__ float lds_l[3][2][64];
    if (kh > 0) {
#pragma unroll
        for (int nf = 0; nf < 4; nf++)
#pragma unroll
            for (int r = 0; r < 4; r++) {
                lds_acc[kh - 1][nf * 4 + r][lane]      = acc0[nf][r];
                lds_acc[kh - 1][16 + nf * 4 + r][lane] = acc1[nf][r];
            }
        lds_l[kh - 1][0][lane] = l0;
        lds_l[kh - 1][1][lane] = l1;
    }
    __syncthreads();
    if (kh == 0) {
#pragma unroll
        for (int q = 0; q < 3; q++) {
#pragma unroll
            for (int nf = 0; nf < 4; nf++)
#pragma unroll
                for (int r = 0; r < 4; r++) {
                    acc0[nf][r] += lds_acc[q][nf * 4 + r][lane];
                    acc1[nf][r] += lds_acc[q][16 + nf * 4 + r][lane];
                }
            l0 += lds_l[q][0][lane];
            l1 += lds_l[q][1][lane];
        }
        l0 += __shfl_xor(l0, 16, 64);
        l0 += __shfl_xor(l0, 32, 64);
        l1 += __shfl_xor(l1, 16, 64);
        l1 += __shfl_xor(l1, 32, 64);
        float lr0[4], lr1[4];
#pragma unroll
        for (int r = 0; r < 4; r++) {
            lr0[r] = __shfl(l0, quad * 4 + r, 64);
            lr1[r] = __shfl(l1, quad * 4 + r, 64);
        }
#pragma unroll
        for (int nf = 0; nf < 4; nf++)
#pragma unroll
            for (int r = 0; r < 4; r++) {
                attn[(((size_t)b * Nq + i0 + quad * 4 + r) * Hq + h) * Fq + nf * 16 + l15] =
                    acc0[nf][r] / lr0[r];
                attn[(((size_t)b * Nq + i0 + 16 + quad * 4 + r) * Hq + h) * Fq + nf * 16 + l15] =
                    acc1[nf][r] / lr1[r];
            }
    }
}

// ---------------------------------------------------------------------------
// Kernel 4: out[b,i,f] = sigmoid( mean_h attn[b,i,h,f] )
// ---------------------------------------------------------------------------
__global__ __launch_bounds__(256) void out_kernel(
    const float* __restrict__ attn, float* __restrict__ out)
{
    const int idx = blockIdx.x * 256 + threadIdx.x;
    const int f   = idx & 63;
    const int bn  = idx >> 6;
    const float* p = attn + (size_t)bn * Hq * Fq + f;
    float s = 0.f;
#pragma unroll
    for (int h = 0; h < Hq; h++) s += p[h * Fq];
    s *= (1.f / Hq);
    out[idx] = 1.f / (1.f + __expf(-s));
}

// ---------------------------------------------------------------------------
extern "C" void kernel_launch(void* const* d_in, const int* in_sizes, int n_in,
                              void* d_out, int out_size, void* d_ws, size_t ws_size,
                              hipStream_t stream) {
    const float* nodes = (const float*)d_in[0];   // (2,2048,512)
    const int*   edges = (const int*)d_in[1];     // (2,2048,2048,1)
    const float* W     = (const float*)d_in[2];   // (512,512)
    const float* a     = (const float*)d_in[3];   // (128,)
    float* out = (float*)d_out;                   // (2,2048,64)

    char* ws = (char*)d_ws;
    ushort* Afrag = (ushort*)ws;           ws += (size_t)Bq * Nq * DIN * 2;           // 4 MB
    ushort* Wfrag = (ushort*)ws;           ws += (size_t)DIN * Hq * Fq * 2;           // 512 KB
    ushort* Vfrag = (ushort*)ws;           ws += (size_t)Bq * Hq * Nq * Fq * 2;       // 4 MB
    float*  el_t  = (float*)ws;            ws += (size_t)Bq * Hq * Nq * 4;            // 128 KB
    float*  er_t  = (float*)ws;            ws += (size_t)Bq * Hq * Nq * 4;            // 128 KB
    unsigned int* ebT = (unsigned int*)ws; ws += (size_t)Bq * (Nq / 32) * Nq * 4;     // 1 MB
    float*  attn  = (float*)ws;                                                       // 16 MB

    prep_kernel<<<AFRAG_BLOCKS + WFRAG_BLOCKS, 256, 0, stream>>>(nodes, Afrag, W, Wfrag);
    work_kernel<<<GEMM_BLOCKS + PACK_BLOCKS, 256, 0, stream>>>(
        Afrag, Wfrag, a, Vfrag, el_t, er_t, edges, ebT);
    attn_kernel<<<Bq * Hq * (Nq / 64), 256, 0, stream>>>(el_t, er_t, Vfrag, ebT, attn);
    out_kernel<<<(Bq * Nq * Fq) / 256, 256, 0, stream>>>(attn, out);
}